// Round 2
// baseline (371.587 us; speedup 1.0000x reference)
//
#include <hip/hip_runtime.h>

typedef unsigned short ushort_t;
typedef short bf16x8 __attribute__((ext_vector_type(8)));
typedef float f32x4 __attribute__((ext_vector_type(4)));

#define DEV __device__ __forceinline__

// round-half-up bf16 (2 ops)
DEV ushort_t f2bf(float f) {
  return (ushort_t)((__float_as_uint(f) + 0x8000u) >> 16);
}
// pack two floats -> 2 bf16 in one u32 (3 ops: add, add, v_perm_b32)
DEV unsigned pk_bf16(float lo, float hi) {
  unsigned a = __float_as_uint(lo) + 0x8000u;
  unsigned b = __float_as_uint(hi) + 0x8000u;
  return __builtin_amdgcn_perm(b, a, 0x07060302);  // {b.hi16, a.hi16}
}
DEV float bf2f(ushort_t h) {
  union { unsigned int u; float f; } v; v.u = ((unsigned int)h) << 16;
  return v.f;
}
DEV f32x4 mfma16(bf16x8 a, bf16x8 b, f32x4 c) {
  return __builtin_amdgcn_mfma_f32_16x16x32_bf16(a, b, c, 0, 0, 0);
}
typedef __attribute__((address_space(3))) void lds_void;
typedef const __attribute__((address_space(1))) void glb_void;
DEV void gl_lds16(const void* g, void* l) {
  __builtin_amdgcn_global_load_lds((glb_void*)g, (lds_void*)l, 16, 0, 0);
}

// ---------------------------------------------------------------------------
// bf16 GEMM: C = A[M,K] * BT[N,K]^T (+bias). 128x128 tile, 4 waves, 4x4 MFMA.
// Columns in [sc_lo, sc_hi) get multiplied by scv after bias (Q pre-scaling).
// Kept for the small-N GEMMs (N=256/512) where 256-tiles would idle CUs.
// ---------------------------------------------------------------------------
__global__ __launch_bounds__(256)
void gemm_bt(const ushort_t* __restrict__ A, int lda,
             const ushort_t* __restrict__ BT,
             const float* __restrict__ bias,
             ushort_t* __restrict__ Cb, float* __restrict__ Cf,
             int ldc, int coff, int K, float scv, int sc_lo, int sc_hi)
{
  __shared__ __align__(16) ushort_t As[128 * 32];
  __shared__ __align__(16) ushort_t Bs[128 * 32];
  const int tid  = threadIdx.x;
  const int wave = tid >> 6, lane = tid & 63;
  const int quad = lane >> 4, r16 = lane & 15;
  const int m0 = blockIdx.x * 128, n0 = blockIdx.y * 128;
  const int wm = (wave >> 1) * 64, wn = (wave & 1) * 64;

  f32x4 acc[4][4];
#pragma unroll
  for (int i = 0; i < 4; ++i)
#pragma unroll
    for (int j = 0; j < 4; ++j) acc[i][j] = (f32x4){0.f, 0.f, 0.f, 0.f};

  for (int kc = 0; kc < K; kc += 32) {
#pragma unroll
    for (int p = 0; p < 4; ++p) {
      int wp = p * 4 + wave;                 // 0..15; 0..7 -> As, 8..15 -> Bs
      int lc = ((wp & 7) << 6) + lane;       // chunk 0..511 within array
      int row = lc >> 2, e8 = (lc & 3) * 8;
      if (wp < 8) gl_lds16(&A[(size_t)(m0 + row) * lda + kc + e8], &As[lc * 8]);
      else        gl_lds16(&BT[(size_t)(n0 + row) * K  + kc + e8], &Bs[lc * 8]);
    }
    __syncthreads();
    bf16x8 af[4], bfr[4];
#pragma unroll
    for (int i = 0; i < 4; ++i) {
      af[i]  = *(const bf16x8*)&As[(wm + i * 16 + r16) * 32 + quad * 8];
      bfr[i] = *(const bf16x8*)&Bs[(wn + i * 16 + r16) * 32 + quad * 8];
    }
#pragma unroll
    for (int mi = 0; mi < 4; ++mi)
#pragma unroll
      for (int ni = 0; ni < 4; ++ni)
        acc[mi][ni] = mfma16(af[mi], bfr[ni], acc[mi][ni]);
    __syncthreads();
  }

  // C/D layout: col = lane&15, row = quad*4 + reg  [m89/m91]
#pragma unroll
  for (int mi = 0; mi < 4; ++mi) {
#pragma unroll
    for (int ni = 0; ni < 4; ++ni) {
      int col = n0 + wn + ni * 16 + r16;
      float bv = bias ? bias[col] : 0.f;
      float s = (col >= sc_lo && col < sc_hi) ? scv : 1.0f;
#pragma unroll
      for (int r = 0; r < 4; ++r) {
        int row = m0 + wm + mi * 16 + quad * 4 + r;
        float v = (acc[mi][ni][r] + bv) * s;
        if (Cf) Cf[(size_t)row * ldc + coff + col] = v;
        else    Cb[(size_t)row * ldc + coff + col] = f2bf(v);
      }
    }
  }
}

// ---------------------------------------------------------------------------
// gemm256: 256x256-tile 8-phase bf16 GEMM (plain-HIP port of the m201
// template). C = A[M,K] * BT[N,K]^T (+bias, +col-scale window).
// 512 threads = 8 waves (2 M x 4 N), per-wave 128x64 output (8x4 frags).
// LDS: 2-deep double-buffered 256x64 A and B tiles = 128 KB.
// Per K-tile (BK=64): 4 phases {ds_read subtile | stage | barrier | setprio |
// 16 MFMA | barrier}. Tile t+1 staged during phases 0-1 of tile t (>= 2
// phases of slack before the boundary drain -> vmcnt(0) there is cheap).
// T2: 3-bit chunk XOR swizzle (chunk ^= row&7) -- same 128 B-row geometry
// proven conflict-free in flash_attn7 round 1. Staging keeps gl_lds16's
// LINEAR dest and inverse-swizzles the GLOBAL source chunk (rule 21).
// Per-wave halves: wm selects A rows [wm*128,+128) (one A-half), wn selects
// B rows [wn*64,+64) (one B-half) -- each wave only reads what it staged a
// full tile ago.
// ---------------------------------------------------------------------------
__global__ __launch_bounds__(512, 2)
void gemm256(const ushort_t* __restrict__ A, int lda,
             const ushort_t* __restrict__ BT,
             const float* __restrict__ bias,
             ushort_t* __restrict__ Cb, float* __restrict__ Cf,
             int ldc, int coff, int K, float scv, int sc_lo, int sc_hi,
             int nbn)
{
  __shared__ __align__(16) ushort_t Ab[2][256 * 64];
  __shared__ __align__(16) ushort_t Bb[2][256 * 64];

  const int tid  = threadIdx.x;
  const int wave = tid >> 6, lane = tid & 63;
  const int quad = lane >> 4, r16 = lane & 15;
  const int wm = wave >> 2, wn = wave & 3;

  // T1: bijective XCD-chunked remap (grid % 8 == 0), then mb-major within a
  // chunk so one XCD shares an A-panel (~2 MB) + full B panel (L2-resident).
  const int nwg = gridDim.x;
  const int lin = blockIdx.x;
  const int logical = (lin & 7) * (nwg >> 3) + (lin >> 3);
  const int mb = logical / nbn, nb = logical - mb * nbn;
  const int m0 = mb * 256, n0 = nb * 256;

  f32x4 acc[8][4];
#pragma unroll
  for (int i = 0; i < 8; ++i)
#pragma unroll
    for (int j = 0; j < 4; ++j) acc[i][j] = (f32x4){0.f, 0.f, 0.f, 0.f};

  // staging: 2048 16B-chunks per 256x64 tile; thread covers 4 per matrix.
  auto stageA = [&](int t, int slot) {
#pragma unroll
    for (int l = 0; l < 4; ++l) {
      int c = l * 512 + tid;               // 0..2047
      int row = c >> 3, cc = c & 7;
      int sc = cc ^ (row & 7);             // inverse-swizzled SOURCE chunk
      gl_lds16(&A[(size_t)(m0 + row) * lda + t * 64 + sc * 8],
               &Ab[slot][c * 8]);
    }
  };
  auto stageB = [&](int t, int slot) {
#pragma unroll
    for (int l = 0; l < 4; ++l) {
      int c = l * 512 + tid;
      int row = c >> 3, cc = c & 7;
      int sc = cc ^ (row & 7);
      gl_lds16(&BT[(size_t)(n0 + row) * K + t * 64 + sc * 8],
               &Bb[slot][c * 8]);
    }
  };
  // swizzled fragment reads: logical chunk (kk*4+quad) of row r is at LDS
  // chunk (kk*4+quad)^(r&7); r&7 == r16&7 within a frag -> 8-lane groups
  // permute all 8 chunk slots (conflict-free).
  auto ldaf = [&](int slot, int row, int kk) -> bf16x8 {
    int ch = ((kk << 2) + quad) ^ (row & 7);
    return *(const bf16x8*)&Ab[slot][row * 64 + ch * 8];
  };
  auto ldbf = [&](int slot, int row, int kk) -> bf16x8 {
    int ch = ((kk << 2) + quad) ^ (row & 7);
    return *(const bf16x8*)&Bb[slot][row * 64 + ch * 8];
  };

  stageA(0, 0);
  stageB(0, 0);
  __syncthreads();

  const int NT = K >> 6;
  bf16x8 bfr[4];
  for (int t = 0; t < NT; ++t) {
    const int cur = t & 1;
    const bool pre = (t + 1 < NT);

    // ---- phase 0: m-half 0, kk=0; prefetch A(t+1)
    {
      bf16x8 af[4];
#pragma unroll
      for (int i = 0; i < 4; ++i) af[i] = ldaf(cur, wm * 128 + i * 16 + r16, 0);
#pragma unroll
      for (int j = 0; j < 4; ++j) bfr[j] = ldbf(cur, wn * 64 + j * 16 + r16, 0);
      if (pre) stageA(t + 1, cur ^ 1);
      __builtin_amdgcn_s_barrier();
      __builtin_amdgcn_s_setprio(1);
#pragma unroll
      for (int i = 0; i < 4; ++i)
#pragma unroll
        for (int j = 0; j < 4; ++j)
          acc[i][j] = mfma16(af[i], bfr[j], acc[i][j]);
      __builtin_amdgcn_s_setprio(0);
      __builtin_amdgcn_s_barrier();
    }
    // ---- phase 1: m-half 1, kk=0; prefetch B(t+1)
    {
      bf16x8 af[4];
#pragma unroll
      for (int i = 0; i < 4; ++i) af[i] = ldaf(cur, wm * 128 + (4 + i) * 16 + r16, 0);
      if (pre) stageB(t + 1, cur ^ 1);
      __builtin_amdgcn_s_barrier();
      __builtin_amdgcn_s_setprio(1);
#pragma unroll
      for (int i = 0; i < 4; ++i)
#pragma unroll
        for (int j = 0; j < 4; ++j)
          acc[4 + i][j] = mfma16(af[i], bfr[j], acc[4 + i][j]);
      __builtin_amdgcn_s_setprio(0);
      __builtin_amdgcn_s_barrier();
    }
    // ---- phase 2: m-half 0, kk=1
    {
      bf16x8 af[4];
#pragma unroll
      for (int i = 0; i < 4; ++i) af[i] = ldaf(cur, wm * 128 + i * 16 + r16, 1);
#pragma unroll
      for (int j = 0; j < 4; ++j) bfr[j] = ldbf(cur, wn * 64 + j * 16 + r16, 1);
      __builtin_amdgcn_s_barrier();
      __builtin_amdgcn_s_setprio(1);
#pragma unroll
      for (int i = 0; i < 4; ++i)
#pragma unroll
        for (int j = 0; j < 4; ++j)
          acc[i][j] = mfma16(af[i], bfr[j], acc[i][j]);
      __builtin_amdgcn_s_setprio(0);
      __builtin_amdgcn_s_barrier();
    }
    // ---- phase 3: m-half 1, kk=1
    {
      bf16x8 af[4];
#pragma unroll
      for (int i = 0; i < 4; ++i) af[i] = ldaf(cur, wm * 128 + (4 + i) * 16 + r16, 1);
      __builtin_amdgcn_s_barrier();
      __builtin_amdgcn_s_setprio(1);
#pragma unroll
      for (int i = 0; i < 4; ++i)
#pragma unroll
        for (int j = 0; j < 4; ++j)
          acc[4 + i][j] = mfma16(af[i], bfr[j], acc[4 + i][j]);
      __builtin_amdgcn_s_setprio(0);
    }
    // tile boundary: drain this wave's t+1 staging loads (issued >= 2 phases
    // ago -> near-free) and fence LDS for all waves.
    __syncthreads();
  }

  // epilogue: C/D layout col = lane&15, row = quad*4 + reg  [m89/m91]
#pragma unroll
  for (int mi = 0; mi < 8; ++mi) {
#pragma unroll
    for (int nj = 0; nj < 4; ++nj) {
      int col = n0 + wn * 64 + nj * 16 + r16;
      float bv = bias ? bias[col] : 0.f;
      float s = (col >= sc_lo && col < sc_hi) ? scv : 1.0f;
#pragma unroll
      for (int r = 0; r < 4; ++r) {
        int row = m0 + wm * 128 + mi * 16 + quad * 4 + r;
        float v = (acc[mi][nj][r] + bv) * s;
        if (Cf) Cf[(size_t)row * ldc + coff + col] = v;
        else    Cb[(size_t)row * ldc + coff + col] = f2bf(v);
      }
    }
  }
}

// ---------------------------------------------------------------------------
// Flash attention v8 (unchanged from round 1; see that round's notes).
// ---------------------------------------------------------------------------
__global__ __launch_bounds__(256)
void flash_attn7(const ushort_t* __restrict__ Q, int qs, int q_ch,
                 const ushort_t* __restrict__ Kg, int ks, int k_ch,
                 const ushort_t* __restrict__ vT,
                 ushort_t* __restrict__ O, int os, int o_ch,
                 int N)
{
  // [buf][64 rows][64 bf16] ; K rows = keys (cols d), V rows = d (cols keys)
  __shared__ __align__(16) ushort_t Ks[2][64 * 64];
  __shared__ __align__(16) ushort_t Vs[2][64 * 64];

  const int H = gridDim.y;
  const int tid = threadIdx.x, wave = tid >> 6, lane = tid & 63;
  const int quad = lane >> 4, c16 = lane & 15;

  // T1: chunked XCD remap (bijective; nwg % 8 == 0).
  const int nwg = gridDim.x * H * gridDim.z;
  const int lin = blockIdx.x + gridDim.x * (blockIdx.y + H * blockIdx.z);
  const int logical = (lin & 7) * (nwg >> 3) + (lin >> 3);
  const int qb = logical & 7;
  const int t8 = logical >> 3;
  const int b = (H == 8) ? (t8 >> 3) : (t8 >> 2);
  const int h = t8 - b * H;
  const int q0 = qb * 128 + wave * 32;

  bf16x8 qf[2][2];
#pragma unroll
  for (int qt = 0; qt < 2; ++qt) {
    const ushort_t* qp = Q + ((size_t)b * N + q0 + qt * 16 + c16) * qs + q_ch + h * 64;
    qf[qt][0] = *(const bf16x8*)&qp[quad * 8];
    qf[qt][1] = *(const bf16x8*)&qp[32 + quad * 8];
  }
  const ushort_t* kbase = Kg + ((size_t)b * N) * ks + k_ch + h * 64;
  const ushort_t* vbase = vT + ((size_t)(b * H + h) * 64) * N;

  f32x4 oacc[2][4];
#pragma unroll
  for (int qt = 0; qt < 2; ++qt)
#pragma unroll
    for (int dt = 0; dt < 4; ++dt) oacc[qt][dt] = (f32x4){0.f, 0.f, 0.f, 0.f};
  float l_acc[2] = {0.f, 0.f};   // per-lane partial sum over this lane's keys

  // bpermute source lanes for the P layout transform:
  // element i of dest quad comes from quad_s = 2*(quad&1) + (i>>1)
  const int laneA = (2 * (quad & 1)) * 16 + c16;
  const int laneB = laneA + 16;

  // swizzled read offsets: logical chunk `quad` of row r lives at LDS chunk
  // quad ^ (r&7); all our read rows have r&7 == c16&7 (loop-invariant).
  const int eo0 = (quad ^ (c16 & 7)) * 8;   // elements; dims/keys quad*8..+7
  const int eo1 = eo0 ^ 32;                 // chunk ^ 4  -> dims/keys +32

  auto stage = [&](int s0, int buf) {
#pragma unroll
    for (int p = 0; p < 4; ++p) {
      int wp = p * 4 + wave;                 // 0..15: 0..7 -> K, 8..15 -> V
      int lc = ((wp & 7) << 6) + lane;       // chunk 0..511 within tile
      int row = lc >> 3, c = lc & 7;
      int e8 = ((c ^ (row & 7)) * 8);        // inverse-swizzled SOURCE chunk
      if (wp < 8) gl_lds16(kbase + (size_t)(s0 + row) * ks + e8, &Ks[buf][lc * 8]);
      else        gl_lds16(vbase + (size_t)row * N + s0 + e8,    &Vs[buf][lc * 8]);
    }
  };

  stage(0, 0);
  const int NT = N >> 6;
  for (int it = 0; it < NT; ++it) {
    const int cur = it & 1;
    __syncthreads();                     // vmcnt(0) drain: tile `it` staged;
                                         // also fences prev-iter LDS readers
    if (it + 1 < NT) stage((it + 1) << 6, cur ^ 1);

    // S^T: A = K rows (m = key si*16+quad*4+r), B = Q (n = query c16).
    f32x4 st[4][2];
#pragma unroll
    for (int si = 0; si < 4; ++si) {
      const ushort_t* kr = &Ks[cur][(si * 16 + c16) * 64];
      bf16x8 kf0 = *(const bf16x8*)&kr[eo0];
      bf16x8 kf1 = *(const bf16x8*)&kr[eo1];
#pragma unroll
      for (int qt = 0; qt < 2; ++qt) {
        f32x4 z = (f32x4){0.f, 0.f, 0.f, 0.f};
        z = mfma16(kf0, qf[qt][0], z);
        z = mfma16(kf1, qf[qt][1], z);
        st[si][qt] = z;
      }
    }

    bf16x8 pA[2], pB[2];               // per qt: keys 0..31 / keys 32..63
#pragma unroll
    for (int qt = 0; qt < 2; ++qt) {
      float tsum = 0.f;
      unsigned pks[4][2];
#pragma unroll
      for (int si = 0; si < 4; ++si) {
        float p0 = __builtin_amdgcn_exp2f(st[si][qt][0]);
        float p1 = __builtin_amdgcn_exp2f(st[si][qt][1]);
        float p2 = __builtin_amdgcn_exp2f(st[si][qt][2]);
        float p3 = __builtin_amdgcn_exp2f(st[si][qt][3]);
        tsum += (p0 + p1) + (p2 + p3);
        pks[si][0] = pk_bf16(p0, p1);      // keys si*16+quad*4+{0,1}
        pks[si][1] = pk_bf16(p2, p3);      // keys si*16+quad*4+{2,3}
      }
      l_acc[qt] += tsum;                   // no cross-lane reduce per iter

      // P -> PV B-operand: B[n=query=c16][k=key=quad*8+j]. Element i (u32,
      // keys {F*32+quad*8+2i, +1}) comes from src lane quad_s=2*(quad&1)+(i>>1)
      // register pks[2F + (quad>>1)][i&1]. Pull BOTH si candidates, select by
      // DEST quad.  [verified R4/R5: absmax 9.8e-4]
      union U8 { bf16x8 f; unsigned u[4]; } pf0, pf1;
      const bool hiq = quad >= 2;
#pragma unroll
      for (int i = 0; i < 4; ++i) {
        int src = (i < 2) ? laneA : laneB;
        unsigned a0 = __shfl(pks[0][i & 1], src);
        unsigned a1 = __shfl(pks[1][i & 1], src);
        unsigned a2 = __shfl(pks[2][i & 1], src);
        unsigned a3 = __shfl(pks[3][i & 1], src);
        pf0.u[i] = hiq ? a1 : a0;
        pf1.u[i] = hiq ? a3 : a2;
      }
      pA[qt] = pf0.f;
      pB[qt] = pf1.f;
    }

    // PV: O^T = mfma(A = V^T (m=d), B = P (n=query)); V read ONCE per dt.
#pragma unroll
    for (int dt = 0; dt < 4; ++dt) {
      const ushort_t* vr = &Vs[cur][(dt * 16 + c16) * 64];
      bf16x8 vf0 = *(const bf16x8*)&vr[eo0];
      bf16x8 vf1 = *(const bf16x8*)&vr[eo1];
#pragma unroll
      for (int qt = 0; qt < 2; ++qt) {
        oacc[qt][dt] = mfma16(vf0, pA[qt], oacc[qt][dt]);
        oacc[qt][dt] = mfma16(vf1, pB[qt], oacc[qt][dt]);
      }
    }
  }

  // epilogue: reduce l across quads once; O^T element r = O[query c16][dt*16+quad*4+r]
#pragma unroll
  for (int qt = 0; qt < 2; ++qt) {
    float l = l_acc[qt];
    l += __shfl_xor(l, 16);
    l += __shfl_xor(l, 32);
    float inv = 1.f / l;
    ushort_t* op = O + ((size_t)b * N + q0 + qt * 16 + c16) * os + o_ch + h * 64;
#pragma unroll
    for (int dt = 0; dt < 4; ++dt) {
      uint2 pkv;
      pkv.x = pk_bf16(oacc[qt][dt][0] * inv, oacc[qt][dt][1] * inv);
      pkv.y = pk_bf16(oacc[qt][dt][2] * inv, oacc[qt][dt][3] * inv);
      *(uint2*)&op[dt * 16 + quad * 4] = pkv;
    }
  }
}

// ---------------------------------------------------------------------------
// V transpose: in [B*N][ld] bf16 (channel ch, head h) -> out [B*H][64][N]
// ---------------------------------------------------------------------------
__global__ __launch_bounds__(256)
void transpose_v(const ushort_t* __restrict__ in, int ld, int ch,
                 ushort_t* __restrict__ out, int N, int H)
{
  __shared__ __align__(16) ushort_t T[64][72];
  const int s0 = blockIdx.x * 64, h = blockIdx.y, b = blockIdx.z;
  const int tid = threadIdx.x;
#pragma unroll
  for (int p = 0; p < 2; ++p) {
    int c = p * 256 + tid;
    int sr = c >> 3, d0 = (c & 7) * 8;
    *(uint4*)&T[sr][d0] =
        *(const uint4*)&in[((size_t)b * N + s0 + sr) * ld + ch + h * 64 + d0];
  }
  __syncthreads();
  const int d = tid >> 2, sp = (tid & 3) * 16;
  union { uint4 v; ushort_t u[8]; } A, B;
#pragma unroll
  for (int j = 0; j < 8; ++j) { A.u[j] = T[sp + j][d]; B.u[j] = T[sp + 8 + j][d]; }
  ushort_t* op = out + ((size_t)(b * H + h) * 64 + d) * N + s0 + sp;
  *(uint4*)&op[0] = A.v;
  *(uint4*)&op[8] = B.v;
}

// ---------------------------------------------------------------------------
// hifi window attention (2x2 windows, 4 heads). qkv rows stride ld; per-token
// layout [3][4 heads][64]. Output stride 512, cols 0..255.
// (q here is NOT pre-scaled by the GEMM; keeps its own 0.125 + __expf.)
// ---------------------------------------------------------------------------
__global__ __launch_bounds__(256)
void hifi_win(const ushort_t* __restrict__ qkv, int ld, ushort_t* __restrict__ out)
{
  const int bg = blockIdx.x;
  const int b = bg >> 8, g = bg & 255;
  const int head = threadIdx.x >> 6, lane = threadIdx.x & 63;
  const int gh = g >> 4, gw = g & 15;

  int n[4];
  float q[4], k[4], v[4];
#pragma unroll
  for (int t = 0; t < 4; ++t) {
    n[t] = (gh * 2 + (t >> 1)) * 32 + gw * 2 + (t & 1);
    size_t base = ((size_t)b * 1024 + n[t]) * ld + head * 64 + lane;
    q[t] = bf2f(qkv[base]);
    k[t] = bf2f(qkv[base + 256]);
    v[t] = bf2f(qkv[base + 512]);
  }
  float sc[4][4];
#pragma unroll
  for (int t = 0; t < 4; ++t)
#pragma unroll
    for (int s = 0; s < 4; ++s) {
      float p = q[t] * k[s];
#pragma unroll
      for (int off = 32; off >= 1; off >>= 1) p += __shfl_xor(p, off);
      sc[t][s] = p * 0.125f;
    }
#pragma unroll
  for (int t = 0; t < 4; ++t) {
    float m = fmaxf(fmaxf(sc[t][0], sc[t][1]), fmaxf(sc[t][2], sc[t][3]));
    float p0 = __expf(sc[t][0] - m), p1 = __expf(sc[t][1] - m);
    float p2 = __expf(sc[t][2] - m), p3 = __expf(sc[t][3] - m);
    float sum = p0 + p1 + p2 + p3;
    float o = (p0 * v[0] + p1 * v[1] + p2 * v[2] + p3 * v[3]) / sum;
    out[((size_t)b * 1024 + n[t]) * 512 + head * 64 + lane] = f2bf(o);
  }
}

// ---------------------------------------------------------------------------
// Merged weight prep: 7 transposes W[K][N] fp32 -> WT[N][K] bf16 in one launch.
// ---------------------------------------------------------------------------
struct WEnt { const float* W; ushort_t* WT; int K; int N; };
struct WArgs { WEnt e[7]; };

__global__ __launch_bounds__(256)
void w_prep(WArgs a)
{
  WEnt w = a.e[blockIdx.z];
  if ((int)blockIdx.x >= (w.K >> 6) || (int)blockIdx.y >= (w.N >> 6)) return;
  __shared__ float T[64][65];
  const int k0 = blockIdx.x * 64, n0 = blockIdx.y * 64;
  const int tid = threadIdx.x;
#pragma unroll
  for (int p = 0; p < 4; ++p) {
    int c = p * 256 + tid;
    int kr = c >> 4, f4 = (c & 15) * 4;
    float4 v = *(const float4*)&w.W[(size_t)(k0 + kr) * w.N + n0 + f4];
    T[f4 + 0][kr] = v.x; T[f4 + 1][kr] = v.y;
    T[f4 + 2][kr] = v.z; T[f4 + 3][kr] = v.w;
  }
  __syncthreads();
  const int nl = tid >> 2, kp = (tid & 3) * 16;
  union { uint4 v; ushort_t u[8]; } A, B;
#pragma unroll
  for (int j = 0; j < 8; ++j) {
    A.u[j] = f2bf(T[nl][kp + j]);
    B.u[j] = f2bf(T[nl][kp + 8 + j]);
  }
  ushort_t* op = w.WT + (size_t)(n0 + nl) * w.K + k0 + kp;
  *(uint4*)&op[0] = A.v;
  *(uint4*)&op[8] = B.v;
}

// xpe = bf16(x + pos_emb), vectorized x4
__global__ void add_pos(const float* __restrict__ x, const float* __restrict__ pos,
                        ushort_t* __restrict__ xpe)
{
  int idx = blockIdx.x * 256 + threadIdx.x;
  int e = idx * 4;
  float4 xv = *(const float4*)&x[e];
  float4 pv = *(const float4*)&pos[e & (512 * 1024 - 1)];
  uint2 pk;
  pk.x = pk_bf16(xv.x + pv.x, xv.y + pv.y);
  pk.y = pk_bf16(xv.z + pv.z, xv.w + pv.w);
  *(uint2*)&xpe[e] = pk;
}

extern "C" void kernel_launch(void* const* d_in, const int* in_sizes, int n_in,
                              void* d_out, int out_size, void* d_ws, size_t ws_size,
                              hipStream_t stream)
{
  const float* x         = (const float*)d_in[0];
  const float* pos       = (const float*)d_in[1];
  const float* l_q_w     = (const float*)d_in[2];
  const float* l_kv_w    = (const float*)d_in[3];
  const float* l_proj_w  = (const float*)d_in[4];
  const float* l_proj_b  = (const float*)d_in[5];
  const float* h_qkv_w   = (const float*)d_in[6];
  const float* h_proj_w  = (const float*)d_in[7];
  const float* h_proj_b  = (const float*)d_in[8];
  const float* in_proj_w = (const float*)d_in[9];
  const float* in_proj_b = (const float*)d_in[10];
  const float* out_proj_w= (const float*)d_in[11];
  const float* out_proj_b= (const float*)d_in[12];
  float* out = (float*)d_out;

  // 0.125 * log2(e): flash_attn uses exp2 directly.
  const float QSCALE = 0.125f * 1.44269504f;

  char* ws = (char*)d_ws;
  ushort_t* xpe = (ushort_t*)(ws);                       // 16 MB @ 0
  ushort_t* y   = (ushort_t*)(ws + (size_t)16777216);    // 16 MB @ 16M
  ushort_t* F   = (ushort_t*)(ws + (size_t)33554432);    // 48 MB @ 32M (fused acts)
  ushort_t* rB  = (ushort_t*)(ws + (size_t)83886080);    // 16 MB @ 80M
  ushort_t* wb  = (ushort_t*)(ws + (size_t)100663296);   // ~4 MB @ 96M (weights)

  // fused BT for the xpe GEMM: rows [0,768)=h_qkv, [768,1024)=l_q, [1024,1536)=l_kv
  ushort_t* F_T      = wb;                        // 1536 x 512
  ushort_t* h_projT  = wb + 786432;               // 256 x 256
  ushort_t* l_projT  = wb + 851968;               // 256 x 256
  ushort_t* in_projT = wb + 917504;               // 1536 x 512
  ushort_t* out_projT= wb + 1703936;              // 512 x 512

  const int M = 16384;
  ushort_t* vT_lo = xpe;   // 8 MB; xpe dead after fused GEMM
  ushort_t* vT_m  = rB;    // 16 MB; rB dead after lproj

  WArgs wa;
  wa.e[0] = {h_qkv_w,   F_T,                 512, 768};
  wa.e[1] = {l_q_w,     F_T + 768 * 512,     512, 256};
  wa.e[2] = {l_kv_w,    F_T + 1024 * 512,    512, 512};
  wa.e[3] = {h_proj_w,  h_projT,             256, 256};
  wa.e[4] = {l_proj_w,  l_projT,             256, 256};
  wa.e[5] = {in_proj_w, in_projT,            512, 1536};
  wa.e[6] = {out_proj_w,out_projT,           512, 512};
  w_prep<<<dim3(8, 24, 7), dim3(256), 0, stream>>>(wa);

  add_pos<<<dim3(8192), dim3(256), 0, stream>>>(x, pos, xpe);

  // 1. fused qkv GEMM: [M,512] x [512,1536] -> F (lofi q cols pre-scaled)
  //    256^2 8-phase: grid 64x6 = 384 blocks (%8==0 for T1 remap)
  gemm256<<<dim3((M / 256) * 6), dim3(512), 0, stream>>>(
      xpe, 512, F_T, nullptr, F, nullptr, 1536, 0, 512, QSCALE, 768, 1024, 6);
  // 2. hifi window attention -> rB cols [0,256)
  hifi_win<<<dim3(4096), dim3(256), 0, stream>>>(F, 1536, rB);
  // 3. transpose lofi V (F cols 1280..1535) -> vT_lo (xpe region, now dead)
  transpose_v<<<dim3(16, 4, 16), dim3(256), 0, stream>>>(
      F, 1536, 1280, vT_lo, 1024, 4);
  // 4. lofi attention (4 heads) -> rB cols [256,512)
  flash_attn7<<<dim3(8, 4, 16), dim3(256), 0, stream>>>(
      F, 1536, 768, F, 1536, 1024, vT_lo, rB, 512, 256, 1024);
  // 5. hifi proj -> y[:, 0:256)
  gemm_bt<<<dim3(M / 128, 2), dim3(256), 0, stream>>>(
      rB, 512, h_projT, h_proj_b, y, nullptr, 512, 0, 256, 1.0f, 0, 0);
  // 6. lofi proj -> y[:, 256:512)
  gemm_bt<<<dim3(M / 128, 2), dim3(256), 0, stream>>>(
      rB + 256, 512, l_projT, l_proj_b, y, nullptr, 512, 256, 256, 1.0f, 0, 0);
  // 7. mha qkv: [M,512] x [512,1536] -> F (q cols pre-scaled)
  gemm256<<<dim3((M / 256) * 6), dim3(512), 0, stream>>>(
      y, 512, in_projT, in_proj_b, F, nullptr, 1536, 0, 512, QSCALE, 0, 512, 6);
  // 8. transpose mha V (F cols 1024..1535) -> vT_m (rB dead now)
  transpose_v<<<dim3(16, 8, 16), dim3(256), 0, stream>>>(
      F, 1536, 1024, vT_m, 1024, 8);
  // 9. mha attention (8 heads) -> xpe region [M,512]
  flash_attn7<<<dim3(8, 8, 16), dim3(256), 0, stream>>>(
      F, 1536, 0, F, 1536, 512, vT_m, xpe, 512, 0, 1024);
  // 10. out proj -> d_out fp32
  gemm_bt<<<dim3(M / 128, 4), dim3(256), 0, stream>>>(
      xpe, 512, out_projT, out_proj_b, nullptr, out, 512, 0, 512, 1.0f, 0, 0);
}

// Round 4
// 348.710 us; speedup vs baseline: 1.0656x; 1.0656x over previous
//
#include <hip/hip_runtime.h>

typedef unsigned short ushort_t;
typedef short bf16x8 __attribute__((ext_vector_type(8)));
typedef float f32x4 __attribute__((ext_vector_type(4)));
typedef float f32x16 __attribute__((ext_vector_type(16)));

#define DEV __device__ __forceinline__

// round-half-up bf16 (2 ops)
DEV ushort_t f2bf(float f) {
  return (ushort_t)((__float_as_uint(f) + 0x8000u) >> 16);
}
// pack two floats -> 2 bf16 in one u32 (3 ops: add, add, v_perm_b32)
DEV unsigned pk_bf16(float lo, float hi) {
  unsigned a = __float_as_uint(lo) + 0x8000u;
  unsigned b = __float_as_uint(hi) + 0x8000u;
  return __builtin_amdgcn_perm(b, a, 0x07060302);  // {b.hi16, a.hi16}
}
DEV float bf2f(ushort_t h) {
  union { unsigned int u; float f; } v; v.u = ((unsigned int)h) << 16;
  return v.f;
}
DEV f32x4 mfma16(bf16x8 a, bf16x8 b, f32x4 c) {
  return __builtin_amdgcn_mfma_f32_16x16x32_bf16(a, b, c, 0, 0, 0);
}
DEV f32x16 mfma32(bf16x8 a, bf16x8 b, f32x16 c) {
  return __builtin_amdgcn_mfma_f32_32x32x16_bf16(a, b, c, 0, 0, 0);
}
// v_permlane32_swap_b32: swaps the UPPER 32 lanes of the first operand with
// the LOWER 32 lanes of the second (LLVM gfx950 semantics).
// After pl32swap(a,b):  a = [a_lo | b_lo],  b = [a_hi | b_hi]   ([lo|hi]).
DEV void pl32swap(unsigned &a, unsigned &b) {
  asm("v_permlane32_swap_b32 %0, %1" : "+v"(a), "+v"(b));
}
typedef __attribute__((address_space(3))) void lds_void;
typedef const __attribute__((address_space(1))) void glb_void;
DEV void gl_lds16(const void* g, void* l) {
  __builtin_amdgcn_global_load_lds((glb_void*)g, (lds_void*)l, 16, 0, 0);
}

// ---------------------------------------------------------------------------
// bf16 GEMM: C = A[M,K] * BT[N,K]^T (+bias). 128x128 tile, 4 waves, 4x4 MFMA.
// Columns in [sc_lo, sc_hi) get multiplied by scv after bias (Q pre-scaling).
// (R2 lesson: the 256^2 8-phase template loses here -- 128 KB LDS forces
// 1 block/CU and the 384-block grid has a 1.5-wave tail. gemm_bt's 16 KB
// LDS + 1536-block grid keeps every CU busy; reverted.)
// ---------------------------------------------------------------------------
__global__ __launch_bounds__(256)
void gemm_bt(const ushort_t* __restrict__ A, int lda,
             const ushort_t* __restrict__ BT,
             const float* __restrict__ bias,
             ushort_t* __restrict__ Cb, float* __restrict__ Cf,
             int ldc, int coff, int K, float scv, int sc_lo, int sc_hi)
{
  __shared__ __align__(16) ushort_t As[128 * 32];
  __shared__ __align__(16) ushort_t Bs[128 * 32];
  const int tid  = threadIdx.x;
  const int wave = tid >> 6, lane = tid & 63;
  const int quad = lane >> 4, r16 = lane & 15;
  const int m0 = blockIdx.x * 128, n0 = blockIdx.y * 128;
  const int wm = (wave >> 1) * 64, wn = (wave & 1) * 64;

  f32x4 acc[4][4];
#pragma unroll
  for (int i = 0; i < 4; ++i)
#pragma unroll
    for (int j = 0; j < 4; ++j) acc[i][j] = (f32x4){0.f, 0.f, 0.f, 0.f};

  for (int kc = 0; kc < K; kc += 32) {
#pragma unroll
    for (int p = 0; p < 4; ++p) {
      int wp = p * 4 + wave;                 // 0..15; 0..7 -> As, 8..15 -> Bs
      int lc = ((wp & 7) << 6) + lane;       // chunk 0..511 within array
      int row = lc >> 2, e8 = (lc & 3) * 8;
      if (wp < 8) gl_lds16(&A[(size_t)(m0 + row) * lda + kc + e8], &As[lc * 8]);
      else        gl_lds16(&BT[(size_t)(n0 + row) * K  + kc + e8], &Bs[lc * 8]);
    }
    __syncthreads();
    bf16x8 af[4], bfr[4];
#pragma unroll
    for (int i = 0; i < 4; ++i) {
      af[i]  = *(const bf16x8*)&As[(wm + i * 16 + r16) * 32 + quad * 8];
      bfr[i] = *(const bf16x8*)&Bs[(wn + i * 16 + r16) * 32 + quad * 8];
    }
#pragma unroll
    for (int mi = 0; mi < 4; ++mi)
#pragma unroll
      for (int ni = 0; ni < 4; ++ni)
        acc[mi][ni] = mfma16(af[mi], bfr[ni], acc[mi][ni]);
    __syncthreads();
  }

  // C/D layout: col = lane&15, row = quad*4 + reg  [m89/m91]
#pragma unroll
  for (int mi = 0; mi < 4; ++mi) {
#pragma unroll
    for (int ni = 0; ni < 4; ++ni) {
      int col = n0 + wn + ni * 16 + r16;
      float bv = bias ? bias[col] : 0.f;
      float s = (col >= sc_lo && col < sc_hi) ? scv : 1.0f;
#pragma unroll
      for (int r = 0; r < 4; ++r) {
        int row = m0 + wm + mi * 16 + quad * 4 + r;
        float v = (acc[mi][ni][r] + bv) * s;
        if (Cf) Cf[(size_t)row * ldc + coff + col] = v;
        else    Cb[(size_t)row * ldc + coff + col] = f2bf(v);
      }
    }
  }
}

// ---------------------------------------------------------------------------
// Flash attention v9b: 32x32x16 MFMA. R3 fix: permlane32_swap operand roles
// matched to the REAL gfx950 semantics (swap(a,b): a=[a_lo|b_lo],
// b=[a_hi|b_hi]). Fragment derivation (from the verified 32x32 C-layout
// col=query=lane&31, row=key=(r&3)+8*(r>>2)+4*(lane>>5)):
//   u[0]=[W0_lo|W2_lo] u[1]=[W1_lo|W3_lo] u[2]=[W0_hi|W2_hi] u[3]=[W1_hi|W3_hi]
// -> swap(W0,W2) yields (u0,u2); swap(W1,W3) yields (u1,u3); W4..W7 for the
// second k-step. 16 pk_bf16 + 4 permlane (VALU) replace v7's 32 ds_bpermute
// + 16 selects (LDS pipe). 16 mfma32 replace 32 mfma16. LDS layout, XOR
// swizzle, staging, double-buffer, barriers: identical to v8.
// NO ONLINE MAX (scores pre-scaled by 0.125*log2e, exp2 fp32-safe; softmax
// shift-invariant). l accumulated per-lane, reduced once at the end.
// ---------------------------------------------------------------------------
__global__ __launch_bounds__(256)
void flash_attn8(const ushort_t* __restrict__ Q, int qs, int q_ch,
                 const ushort_t* __restrict__ Kg, int ks, int k_ch,
                 const ushort_t* __restrict__ vT,
                 ushort_t* __restrict__ O, int os, int o_ch,
                 int N)
{
  // [buf][64 rows][64 bf16] ; K rows = keys (cols d), V rows = d (cols keys)
  __shared__ __align__(16) ushort_t Ks[2][64 * 64];
  __shared__ __align__(16) ushort_t Vs[2][64 * 64];

  const int H = gridDim.y;
  const int tid = threadIdx.x, wave = tid >> 6, lane = tid & 63;
  const int c = lane & 31, hh = lane >> 5;

  // T1: chunked XCD remap (bijective; nwg % 8 == 0).
  const int nwg = gridDim.x * H * gridDim.z;
  const int lin = blockIdx.x + gridDim.x * (blockIdx.y + H * blockIdx.z);
  const int logical = (lin & 7) * (nwg >> 3) + (lin >> 3);
  const int qb = logical & 7;
  const int t8 = logical >> 3;
  const int b = (H == 8) ? (t8 >> 3) : (t8 >> 2);
  const int h = t8 - b * H;
  const int q0 = qb * 128 + wave * 32;

  // Q fragments: B-operand layout B[k=d][n=query]: lane (hh,c) holds
  // query q0+c, d = s*16 + hh*8 + j  ->  qf[s] at byte-col s*16 + hh*8.
  bf16x8 qf[4];
  {
    const ushort_t* qp = Q + ((size_t)b * N + q0 + c) * qs + q_ch + h * 64 + hh * 8;
#pragma unroll
    for (int s = 0; s < 4; ++s) qf[s] = *(const bf16x8*)&qp[s * 16];
  }
  const ushort_t* kbase = Kg + ((size_t)b * N) * ks + k_ch + h * 64;
  const ushort_t* vbase = vT + ((size_t)(b * H + h) * 64) * N;

  f32x16 oacc[2];
#pragma unroll
  for (int i = 0; i < 16; ++i) { oacc[0][i] = 0.f; oacc[1][i] = 0.f; }
  float l_acc = 0.f;   // per-lane partial sum over this lane's keys

  auto stage = [&](int s0, int buf) {
#pragma unroll
    for (int p = 0; p < 4; ++p) {
      int wp = p * 4 + wave;                 // 0..15: 0..7 -> K, 8..15 -> V
      int lc = ((wp & 7) << 6) + lane;       // chunk 0..511 within tile
      int row = lc >> 3, cc = lc & 7;
      int e8 = ((cc ^ (row & 7)) * 8);       // inverse-swizzled SOURCE chunk
      if (wp < 8) gl_lds16(kbase + (size_t)(s0 + row) * ks + e8, &Ks[buf][lc * 8]);
      else        gl_lds16(vbase + (size_t)row * N + s0 + e8,    &Vs[buf][lc * 8]);
    }
  };

  stage(0, 0);
  const int NT = N >> 6;
  for (int it = 0; it < NT; ++it) {
    const int cur = it & 1;
    __syncthreads();                     // vmcnt(0) drain: tile `it` staged;
                                         // also fences prev-iter LDS readers
    if (it + 1 < NT) stage((it + 1) << 6, cur ^ 1);

    bf16x8 Bf[4];                        // PV B-operand, k-steps of 16 keys
#pragma unroll
    for (int kb = 0; kb < 2; ++kb) {
      // S^T block: A = K rows (m = key kb*32 + (lane&31)), B = Q.
      f32x16 z;
#pragma unroll
      for (int i = 0; i < 16; ++i) z[i] = 0.f;
      const int krow = kb * 32 + c;
      const ushort_t* kr = &Ks[cur][krow * 64];
#pragma unroll
      for (int s = 0; s < 4; ++s) {
        bf16x8 kf = *(const bf16x8*)&kr[(((s << 1) + hh) ^ (krow & 7)) * 8];
        z = mfma32(kf, qf[s], z);
      }
      // exp + pack: reg r <-> key kb*32 + (r&3) + 8*(r>>2) + 4*hh
      float ts = 0.f;
      unsigned W[8];
#pragma unroll
      for (int t = 0; t < 8; ++t) {
        float p0 = __builtin_amdgcn_exp2f(z[2 * t]);
        float p1 = __builtin_amdgcn_exp2f(z[2 * t + 1]);
        ts += p0 + p1;
        W[t] = pk_bf16(p0, p1);
      }
      l_acc += ts;
      // B[k=hh*8+j][n=c] per k-step, element i = keys {s*16+hh*8+2i, +1}:
      //   u0=[W0_lo|W2_lo] u1=[W1_lo|W3_lo] u2=[W0_hi|W2_hi] u3=[W1_hi|W3_hi]
      // swap(a,b): a=[a_lo|b_lo], b=[a_hi|b_hi]  ->  swap(W0,W2)=(u0,u2),
      // swap(W1,W3)=(u1,u3); W4..W7 for the second k-step.
      union U8 { bf16x8 f; unsigned u[4]; } f0, f1;
      unsigned a0 = W[0], b0 = W[2]; pl32swap(a0, b0);
      unsigned a1 = W[1], b1 = W[3]; pl32swap(a1, b1);
      f0.u[0] = a0; f0.u[1] = a1; f0.u[2] = b0; f0.u[3] = b1;
      unsigned a2 = W[4], b2 = W[6]; pl32swap(a2, b2);
      unsigned a3 = W[5], b3 = W[7]; pl32swap(a3, b3);
      f1.u[0] = a2; f1.u[1] = a3; f1.u[2] = b2; f1.u[3] = b3;
      Bf[kb * 2]     = f0.f;
      Bf[kb * 2 + 1] = f1.f;
    }

    // PV: O^T = mfma32(A = V^T (m = d), B = P), k-steps of 16 keys.
#pragma unroll
    for (int db = 0; db < 2; ++db) {
      const int vrow = db * 32 + c;
      const ushort_t* vr = &Vs[cur][vrow * 64];
#pragma unroll
      for (int s = 0; s < 4; ++s) {
        bf16x8 vf = *(const bf16x8*)&vr[(((s << 1) + hh) ^ (vrow & 7)) * 8];
        oacc[db] = mfma32(vf, Bf[s], oacc[db]);
      }
    }
  }

  // epilogue: l(query c) = l_acc(h0) + l_acc(h1); O^T reg r of dblk db is
  // d = db*32 + (r&3) + 8*(r>>2) + 4*hh, query = c.
  float l = l_acc + __shfl_xor(l_acc, 32);
  float inv = 1.f / l;
  ushort_t* op = O + ((size_t)b * N + q0 + c) * os + o_ch + h * 64;
#pragma unroll
  for (int db = 0; db < 2; ++db) {
#pragma unroll
    for (int g = 0; g < 4; ++g) {
      uint2 pkv;
      pkv.x = pk_bf16(oacc[db][4 * g + 0] * inv, oacc[db][4 * g + 1] * inv);
      pkv.y = pk_bf16(oacc[db][4 * g + 2] * inv, oacc[db][4 * g + 3] * inv);
      *(uint2*)&op[db * 32 + g * 8 + hh * 4] = pkv;
    }
  }
}

// ---------------------------------------------------------------------------
// V transpose: in [B*N][ld] bf16 (channel ch, head h) -> out [B*H][64][N]
// ---------------------------------------------------------------------------
__global__ __launch_bounds__(256)
void transpose_v(const ushort_t* __restrict__ in, int ld, int ch,
                 ushort_t* __restrict__ out, int N, int H)
{
  __shared__ __align__(16) ushort_t T[64][72];
  const int s0 = blockIdx.x * 64, h = blockIdx.y, b = blockIdx.z;
  const int tid = threadIdx.x;
#pragma unroll
  for (int p = 0; p < 2; ++p) {
    int c = p * 256 + tid;
    int sr = c >> 3, d0 = (c & 7) * 8;
    *(uint4*)&T[sr][d0] =
        *(const uint4*)&in[((size_t)b * N + s0 + sr) * ld + ch + h * 64 + d0];
  }
  __syncthreads();
  const int d = tid >> 2, sp = (tid & 3) * 16;
  union { uint4 v; ushort_t u[8]; } A, B;
#pragma unroll
  for (int j = 0; j < 8; ++j) { A.u[j] = T[sp + j][d]; B.u[j] = T[sp + 8 + j][d]; }
  ushort_t* op = out + ((size_t)(b * H + h) * 64 + d) * N + s0 + sp;
  *(uint4*)&op[0] = A.v;
  *(uint4*)&op[8] = B.v;
}

// ---------------------------------------------------------------------------
// hifi window attention (2x2 windows, 4 heads). qkv rows stride ld; per-token
// layout [3][4 heads][64]. Output stride 512, cols 0..255.
// (q here is NOT pre-scaled by the GEMM; keeps its own 0.125 + __expf.)
// ---------------------------------------------------------------------------
__global__ __launch_bounds__(256)
void hifi_win(const ushort_t* __restrict__ qkv, int ld, ushort_t* __restrict__ out)
{
  const int bg = blockIdx.x;
  const int b = bg >> 8, g = bg & 255;
  const int head = threadIdx.x >> 6, lane = threadIdx.x & 63;
  const int gh = g >> 4, gw = g & 15;

  int n[4];
  float q[4], k[4], v[4];
#pragma unroll
  for (int t = 0; t < 4; ++t) {
    n[t] = (gh * 2 + (t >> 1)) * 32 + gw * 2 + (t & 1);
    size_t base = ((size_t)b * 1024 + n[t]) * ld + head * 64 + lane;
    q[t] = bf2f(qkv[base]);
    k[t] = bf2f(qkv[base + 256]);
    v[t] = bf2f(qkv[base + 512]);
  }
  float sc[4][4];
#pragma unroll
  for (int t = 0; t < 4; ++t)
#pragma unroll
    for (int s = 0; s < 4; ++s) {
      float p = q[t] * k[s];
#pragma unroll
      for (int off = 32; off >= 1; off >>= 1) p += __shfl_xor(p, off);
      sc[t][s] = p * 0.125f;
    }
#pragma unroll
  for (int t = 0; t < 4; ++t) {
    float m = fmaxf(fmaxf(sc[t][0], sc[t][1]), fmaxf(sc[t][2], sc[t][3]));
    float p0 = __expf(sc[t][0] - m), p1 = __expf(sc[t][1] - m);
    float p2 = __expf(sc[t][2] - m), p3 = __expf(sc[t][3] - m);
    float sum = p0 + p1 + p2 + p3;
    float o = (p0 * v[0] + p1 * v[1] + p2 * v[2] + p3 * v[3]) / sum;
    out[((size_t)b * 1024 + n[t]) * 512 + head * 64 + lane] = f2bf(o);
  }
}

// ---------------------------------------------------------------------------
// Merged weight prep: 7 transposes W[K][N] fp32 -> WT[N][K] bf16 in one launch.
// ---------------------------------------------------------------------------
struct WEnt { const float* W; ushort_t* WT; int K; int N; };
struct WArgs { WEnt e[7]; };

__global__ __launch_bounds__(256)
void w_prep(WArgs a)
{
  WEnt w = a.e[blockIdx.z];
  if ((int)blockIdx.x >= (w.K >> 6) || (int)blockIdx.y >= (w.N >> 6)) return;
  __shared__ float T[64][65];
  const int k0 = blockIdx.x * 64, n0 = blockIdx.y * 64;
  const int tid = threadIdx.x;
#pragma unroll
  for (int p = 0; p < 4; ++p) {
    int c = p * 256 + tid;
    int kr = c >> 4, f4 = (c & 15) * 4;
    float4 v = *(const float4*)&w.W[(size_t)(k0 + kr) * w.N + n0 + f4];
    T[f4 + 0][kr] = v.x; T[f4 + 1][kr] = v.y;
    T[f4 + 2][kr] = v.z; T[f4 + 3][kr] = v.w;
  }
  __syncthreads();
  const int nl = tid >> 2, kp = (tid & 3) * 16;
  union { uint4 v; ushort_t u[8]; } A, B;
#pragma unroll
  for (int j = 0; j < 8; ++j) {
    A.u[j] = f2bf(T[nl][kp + j]);
    B.u[j] = f2bf(T[nl][kp + 8 + j]);
  }
  ushort_t* op = w.WT + (size_t)(n0 + nl) * w.K + k0 + kp;
  *(uint4*)&op[0] = A.v;
  *(uint4*)&op[8] = B.v;
}

// xpe = bf16(x + pos_emb), vectorized x4
__global__ void add_pos(const float* __restrict__ x, const float* __restrict__ pos,
                        ushort_t* __restrict__ xpe)
{
  int idx = blockIdx.x * 256 + threadIdx.x;
  int e = idx * 4;
  float4 xv = *(const float4*)&x[e];
  float4 pv = *(const float4*)&pos[e & (512 * 1024 - 1)];
  uint2 pk;
  pk.x = pk_bf16(xv.x + pv.x, xv.y + pv.y);
  pk.y = pk_bf16(xv.z + pv.z, xv.w + pv.w);
  *(uint2*)&xpe[e] = pk;
}

extern "C" void kernel_launch(void* const* d_in, const int* in_sizes, int n_in,
                              void* d_out, int out_size, void* d_ws, size_t ws_size,
                              hipStream_t stream)
{
  const float* x         = (const float*)d_in[0];
  const float* pos       = (const float*)d_in[1];
  const float* l_q_w     = (const float*)d_in[2];
  const float* l_kv_w    = (const float*)d_in[3];
  const float* l_proj_w  = (const float*)d_in[4];
  const float* l_proj_b  = (const float*)d_in[5];
  const float* h_qkv_w   = (const float*)d_in[6];
  const float* h_proj_w  = (const float*)d_in[7];
  const float* h_proj_b  = (const float*)d_in[8];
  const float* in_proj_w = (const float*)d_in[9];
  const float* in_proj_b = (const float*)d_in[10];
  const float* out_proj_w= (const float*)d_in[11];
  const float* out_proj_b= (const float*)d_in[12];
  float* out = (float*)d_out;

  // 0.125 * log2(e): flash_attn uses exp2 directly.
  const float QSCALE = 0.125f * 1.44269504f;

  char* ws = (char*)d_ws;
  ushort_t* xpe = (ushort_t*)(ws);                       // 16 MB @ 0
  ushort_t* y   = (ushort_t*)(ws + (size_t)16777216);    // 16 MB @ 16M
  ushort_t* F   = (ushort_t*)(ws + (size_t)33554432);    // 48 MB @ 32M (fused acts)
  ushort_t* rB  = (ushort_t*)(ws + (size_t)83886080);    // 16 MB @ 80M
  ushort_t* wb  = (ushort_t*)(ws + (size_t)100663296);   // ~4 MB @ 96M (weights)

  // fused BT for the xpe GEMM: rows [0,768)=h_qkv, [768,1024)=l_q, [1024,1536)=l_kv
  ushort_t* F_T      = wb;                        // 1536 x 512
  ushort_t* h_projT  = wb + 786432;               // 256 x 256
  ushort_t* l_projT  = wb + 851968;               // 256 x 256
  ushort_t* in_projT = wb + 917504;               // 1536 x 512
  ushort_t* out_projT= wb + 1703936;              // 512 x 512

  const int M = 16384;
  ushort_t* vT_lo = xpe;   // 8 MB; xpe dead after fused GEMM
  ushort_t* vT_m  = rB;    // 16 MB; rB dead after lproj

  WArgs wa;
  wa.e[0] = {h_qkv_w,   F_T,                 512, 768};
  wa.e[1] = {l_q_w,     F_T + 768 * 512,     512, 256};
  wa.e[2] = {l_kv_w,    F_T + 1024 * 512,    512, 512};
  wa.e[3] = {h_proj_w,  h_projT,             256, 256};
  wa.e[4] = {l_proj_w,  l_projT,             256, 256};
  wa.e[5] = {in_proj_w, in_projT,            512, 1536};
  wa.e[6] = {out_proj_w,out_projT,           512, 512};
  w_prep<<<dim3(8, 24, 7), dim3(256), 0, stream>>>(wa);

  add_pos<<<dim3(8192), dim3(256), 0, stream>>>(x, pos, xpe);

  // 1. fused qkv GEMM: [M,512] x [512,1536] -> F (lofi q cols pre-scaled)
  gemm_bt<<<dim3(M / 128, 12), dim3(256), 0, stream>>>(
      xpe, 512, F_T, nullptr, F, nullptr, 1536, 0, 512, QSCALE, 768, 1024);
  // 2. hifi window attention -> rB cols [0,256)
  hifi_win<<<dim3(4096), dim3(256), 0, stream>>>(F, 1536, rB);
  // 3. transpose lofi V (F cols 1280..1535) -> vT_lo (xpe region, now dead)
  transpose_v<<<dim3(16, 4, 16), dim3(256), 0, stream>>>(
      F, 1536, 1280, vT_lo, 1024, 4);
  // 4. lofi attention (4 heads) -> rB cols [256,512)
  flash_attn8<<<dim3(8, 4, 16), dim3(256), 0, stream>>>(
      F, 1536, 768, F, 1536, 1024, vT_lo, rB, 512, 256, 1024);
  // 5. hifi proj -> y[:, 0:256)
  gemm_bt<<<dim3(M / 128, 2), dim3(256), 0, stream>>>(
      rB, 512, h_projT, h_proj_b, y, nullptr, 512, 0, 256, 1.0f, 0, 0);
  // 6. lofi proj -> y[:, 256:512)
  gemm_bt<<<dim3(M / 128, 2), dim3(256), 0, stream>>>(
      rB + 256, 512, l_projT, l_proj_b, y, nullptr, 512, 256, 256, 1.0f, 0, 0);
  // 7. mha qkv: [M,512] x [512,1536] -> F (q cols pre-scaled)
  gemm_bt<<<dim3(M / 128, 12), dim3(256), 0, stream>>>(
      y, 512, in_projT, in_proj_b, F, nullptr, 1536, 0, 512, QSCALE, 0, 512);
  // 8. transpose mha V (F cols 1024..1535) -> vT_m (rB dead now)
  transpose_v<<<dim3(16, 8, 16), dim3(256), 0, stream>>>(
      F, 1536, 1024, vT_m, 1024, 8);
  // 9. mha attention (8 heads) -> xpe region [M,512]
  flash_attn8<<<dim3(8, 8, 16), dim3(256), 0, stream>>>(
      F, 1536, 0, F, 1536, 512, vT_m, xpe, 512, 0, 1024);
  // 10. out proj -> d_out fp32
  gemm_bt<<<dim3(M / 128, 4), dim3(256), 0, stream>>>(
      xpe, 512, out_projT, out_proj_b, nullptr, out, 512, 0, 512, 1.0f, 0, 0);
}

// Round 5
// 335.384 us; speedup vs baseline: 1.1079x; 1.0397x over previous
//
#include <hip/hip_runtime.h>

typedef unsigned short ushort_t;
typedef short bf16x8 __attribute__((ext_vector_type(8)));
typedef float f32x4 __attribute__((ext_vector_type(4)));
typedef float f32x16 __attribute__((ext_vector_type(16)));

#define DEV __device__ __forceinline__

// round-half-up bf16 (2 ops)
DEV ushort_t f2bf(float f) {
  return (ushort_t)((__float_as_uint(f) + 0x8000u) >> 16);
}
// pack two floats -> 2 bf16 in one u32 (3 ops: add, add, v_perm_b32)
DEV unsigned pk_bf16(float lo, float hi) {
  unsigned a = __float_as_uint(lo) + 0x8000u;
  unsigned b = __float_as_uint(hi) + 0x8000u;
  return __builtin_amdgcn_perm(b, a, 0x07060302);  // {b.hi16, a.hi16}
}
DEV float bf2f(ushort_t h) {
  union { unsigned int u; float f; } v; v.u = ((unsigned int)h) << 16;
  return v.f;
}
DEV f32x4 mfma16(bf16x8 a, bf16x8 b, f32x4 c) {
  return __builtin_amdgcn_mfma_f32_16x16x32_bf16(a, b, c, 0, 0, 0);
}
DEV f32x16 mfma32(bf16x8 a, bf16x8 b, f32x16 c) {
  return __builtin_amdgcn_mfma_f32_32x32x16_bf16(a, b, c, 0, 0, 0);
}
// v_permlane32_swap_b32: swaps the UPPER 32 lanes of the first operand with
// the LOWER 32 lanes of the second (gfx950 semantics, verified R4).
// After pl32swap(a,b):  a = [a_lo | b_lo],  b = [a_hi | b_hi]   ([lo|hi]).
DEV void pl32swap(unsigned &a, unsigned &b) {
  asm("v_permlane32_swap_b32 %0, %1" : "+v"(a), "+v"(b));
}
typedef __attribute__((address_space(3))) void lds_void;
typedef const __attribute__((address_space(1))) void glb_void;
DEV void gl_lds16(const void* g, void* l) {
  __builtin_amdgcn_global_load_lds((glb_void*)g, (lds_void*)l, 16, 0, 0);
}

// ---------------------------------------------------------------------------
// bf16 GEMM: C = A[M,K] * BT[N,K]^T (+bias). 128x128 tile, 4 waves, 4x4 MFMA.
// Columns in [sc_lo, sc_hi) get multiplied by scv after bias (Q pre-scaling).
// (R2 lesson: the 256^2 8-phase template loses here -- 128 KB LDS forces
// 1 block/CU and the 384-block grid has a 1.5-wave tail. gemm_bt's 16 KB
// LDS + 1536-block grid keeps every CU busy; reverted.)
// ---------------------------------------------------------------------------
__global__ __launch_bounds__(256)
void gemm_bt(const ushort_t* __restrict__ A, int lda,
             const ushort_t* __restrict__ BT,
             const float* __restrict__ bias,
             ushort_t* __restrict__ Cb, float* __restrict__ Cf,
             int ldc, int coff, int K, float scv, int sc_lo, int sc_hi)
{
  __shared__ __align__(16) ushort_t As[128 * 32];
  __shared__ __align__(16) ushort_t Bs[128 * 32];
  const int tid  = threadIdx.x;
  const int wave = tid >> 6, lane = tid & 63;
  const int quad = lane >> 4, r16 = lane & 15;
  const int m0 = blockIdx.x * 128, n0 = blockIdx.y * 128;
  const int wm = (wave >> 1) * 64, wn = (wave & 1) * 64;

  f32x4 acc[4][4];
#pragma unroll
  for (int i = 0; i < 4; ++i)
#pragma unroll
    for (int j = 0; j < 4; ++j) acc[i][j] = (f32x4){0.f, 0.f, 0.f, 0.f};

  for (int kc = 0; kc < K; kc += 32) {
#pragma unroll
    for (int p = 0; p < 4; ++p) {
      int wp = p * 4 + wave;                 // 0..15; 0..7 -> As, 8..15 -> Bs
      int lc = ((wp & 7) << 6) + lane;       // chunk 0..511 within array
      int row = lc >> 2, e8 = (lc & 3) * 8;
      if (wp < 8) gl_lds16(&A[(size_t)(m0 + row) * lda + kc + e8], &As[lc * 8]);
      else        gl_lds16(&BT[(size_t)(n0 + row) * K  + kc + e8], &Bs[lc * 8]);
    }
    __syncthreads();
    bf16x8 af[4], bfr[4];
#pragma unroll
    for (int i = 0; i < 4; ++i) {
      af[i]  = *(const bf16x8*)&As[(wm + i * 16 + r16) * 32 + quad * 8];
      bfr[i] = *(const bf16x8*)&Bs[(wn + i * 16 + r16) * 32 + quad * 8];
    }
#pragma unroll
    for (int mi = 0; mi < 4; ++mi)
#pragma unroll
      for (int ni = 0; ni < 4; ++ni)
        acc[mi][ni] = mfma16(af[mi], bfr[ni], acc[mi][ni]);
    __syncthreads();
  }

  // C/D layout: col = lane&15, row = quad*4 + reg  [m89/m91]
#pragma unroll
  for (int mi = 0; mi < 4; ++mi) {
#pragma unroll
    for (int ni = 0; ni < 4; ++ni) {
      int col = n0 + wn + ni * 16 + r16;
      float bv = bias ? bias[col] : 0.f;
      float s = (col >= sc_lo && col < sc_hi) ? scv : 1.0f;
#pragma unroll
      for (int r = 0; r < 4; ++r) {
        int row = m0 + wm + mi * 16 + quad * 4 + r;
        float v = (acc[mi][ni][r] + bv) * s;
        if (Cf) Cf[(size_t)row * ldc + coff + col] = v;
        else    Cb[(size_t)row * ldc + coff + col] = f2bf(v);
      }
    }
  }
}

// ---------------------------------------------------------------------------
// Flash attention v10: QG independent 32-query groups per wave (templated).
// R4 diagnosis: at ~22% occupancy (<2 waves/SIMD) the per-wave serial chain
// (K-read -> QK MFMA -> exp/pack -> PV MFMA) leaves ~50% of cycles as
// latency stall. QG=2 gives each wave two independent chains (ILP where TLP
// is short): qg0's softmax overlaps qg1's MFMA, and K/V ds_reads, staging
// volume, and barrier count per score all halve. QG=1 is byte-equivalent to
// the R4 kernel (kept for lofi: 256 blocks at QG=2 would be 1 block/CU).
// Note: SQ_LDS_BANK_CONFLICT == 16 cyc per gl_lds16 write burst (fixed DMA
// property, measured R1/R4 invariant) -- not a layout issue; ds_reads are
// conflict-free under the 3-bit XOR swizzle.
// 32x32x16 MFMA; S^T = mfma32(K, Q), C-layout col=query=lane&31,
// row=key=(r&3)+8*(r>>2)+4*(lane>>5). P-transform: 16 pk_bf16 + 4
// permlane32_swap per group-tile. NO ONLINE MAX (scores pre-scaled by
// 0.125*log2e in the QKV GEMM; exp2 fp32-safe; softmax shift-invariant).
// ---------------------------------------------------------------------------
template<int QG>
__global__ __launch_bounds__(256, 2)
void flash_attn9(const ushort_t* __restrict__ Q, int qs, int q_ch,
                 const ushort_t* __restrict__ Kg, int ks, int k_ch,
                 const ushort_t* __restrict__ vT,
                 ushort_t* __restrict__ O, int os, int o_ch,
                 int N)
{
  // [buf][64 rows][64 bf16] ; K rows = keys (cols d), V rows = d (cols keys)
  __shared__ __align__(16) ushort_t Ks[2][64 * 64];
  __shared__ __align__(16) ushort_t Vs[2][64 * 64];

  const int H = gridDim.y;
  const int tid = threadIdx.x, wave = tid >> 6, lane = tid & 63;
  const int c = lane & 31, hh = lane >> 5;

  // T1: chunked XCD remap (bijective; nwg % 8 == 0).
  const int nwg = gridDim.x * H * gridDim.z;
  const int lin = blockIdx.x + gridDim.x * (blockIdx.y + H * blockIdx.z);
  const int logical = (lin & 7) * (nwg >> 3) + (lin >> 3);
  const int QBS = 8 / QG;                  // q-blocks per (b,h)
  const int qb = logical & (QBS - 1);
  const int t8 = logical / QBS;
  const int b = (H == 8) ? (t8 >> 3) : (t8 >> 2);
  const int h = t8 - b * H;
  const int q0 = qb * (128 * QG) + wave * (32 * QG);

  // Q fragments: B-operand layout B[k=d][n=query]: lane (hh,c) holds
  // query q0+qg*32+c, d = s*16 + hh*8 + j -> qf[qg][s] at byte-col s*16+hh*8.
  bf16x8 qf[QG][4];
#pragma unroll
  for (int qg = 0; qg < QG; ++qg) {
    const ushort_t* qp =
        Q + ((size_t)b * N + q0 + qg * 32 + c) * qs + q_ch + h * 64 + hh * 8;
#pragma unroll
    for (int s = 0; s < 4; ++s) qf[qg][s] = *(const bf16x8*)&qp[s * 16];
  }
  const ushort_t* kbase = Kg + ((size_t)b * N) * ks + k_ch + h * 64;
  const ushort_t* vbase = vT + ((size_t)(b * H + h) * 64) * N;

  f32x16 oacc[QG][2];
#pragma unroll
  for (int qg = 0; qg < QG; ++qg)
#pragma unroll
    for (int i = 0; i < 16; ++i) { oacc[qg][0][i] = 0.f; oacc[qg][1][i] = 0.f; }
  float l_acc[QG];
#pragma unroll
  for (int qg = 0; qg < QG; ++qg) l_acc[qg] = 0.f;

  auto stage = [&](int s0, int buf) {
#pragma unroll
    for (int p = 0; p < 4; ++p) {
      int wp = p * 4 + wave;                 // 0..15: 0..7 -> K, 8..15 -> V
      int lc = ((wp & 7) << 6) + lane;       // chunk 0..511 within tile
      int row = lc >> 3, cc = lc & 7;
      int e8 = ((cc ^ (row & 7)) * 8);       // inverse-swizzled SOURCE chunk
      if (wp < 8) gl_lds16(kbase + (size_t)(s0 + row) * ks + e8, &Ks[buf][lc * 8]);
      else        gl_lds16(vbase + (size_t)row * N + s0 + e8,    &Vs[buf][lc * 8]);
    }
  };

  stage(0, 0);
  const int NT = N >> 6;
  for (int it = 0; it < NT; ++it) {
    const int cur = it & 1;
    __syncthreads();                     // vmcnt(0) drain: tile `it` staged;
                                         // also fences prev-iter LDS readers
    if (it + 1 < NT) stage((it + 1) << 6, cur ^ 1);

    bf16x8 Bf[QG][4];                    // PV B-operand, k-steps of 16 keys
#pragma unroll
    for (int kb = 0; kb < 2; ++kb) {
      // K fragments shared across the QG query groups.
      const int krow = kb * 32 + c;
      const ushort_t* kr = &Ks[cur][krow * 64];
      bf16x8 kf[4];
#pragma unroll
      for (int s = 0; s < 4; ++s)
        kf[s] = *(const bf16x8*)&kr[(((s << 1) + hh) ^ (krow & 7)) * 8];

#pragma unroll
      for (int qg = 0; qg < QG; ++qg) {
        // S^T block: A = K rows (m = key kb*32 + (lane&31)), B = Q[qg].
        f32x16 z;
#pragma unroll
        for (int i = 0; i < 16; ++i) z[i] = 0.f;
#pragma unroll
        for (int s = 0; s < 4; ++s) z = mfma32(kf[s], qf[qg][s], z);
        // exp + pack: reg r <-> key kb*32 + (r&3) + 8*(r>>2) + 4*hh
        float ts = 0.f;
        unsigned W[8];
#pragma unroll
        for (int t = 0; t < 8; ++t) {
          float p0 = __builtin_amdgcn_exp2f(z[2 * t]);
          float p1 = __builtin_amdgcn_exp2f(z[2 * t + 1]);
          ts += p0 + p1;
          W[t] = pk_bf16(p0, p1);
        }
        l_acc[qg] += ts;
        // B[k=hh*8+j][n=c] per k-step, element i = keys {s*16+hh*8+2i, +1}:
        //  u0=[W0_lo|W2_lo] u1=[W1_lo|W3_lo] u2=[W0_hi|W2_hi] u3=[W1_hi|W3_hi]
        // swap(a,b): a=[a_lo|b_lo], b=[a_hi|b_hi] -> swap(W0,W2)=(u0,u2),
        // swap(W1,W3)=(u1,u3); W4..W7 for the second k-step.  [verified R4]
        union U8 { bf16x8 f; unsigned u[4]; } f0, f1;
        unsigned a0 = W[0], b0 = W[2]; pl32swap(a0, b0);
        unsigned a1 = W[1], b1 = W[3]; pl32swap(a1, b1);
        f0.u[0] = a0; f0.u[1] = a1; f0.u[2] = b0; f0.u[3] = b1;
        unsigned a2 = W[4], b2 = W[6]; pl32swap(a2, b2);
        unsigned a3 = W[5], b3 = W[7]; pl32swap(a3, b3);
        f1.u[0] = a2; f1.u[1] = a3; f1.u[2] = b2; f1.u[3] = b3;
        Bf[qg][kb * 2]     = f0.f;
        Bf[qg][kb * 2 + 1] = f1.f;
      }
    }

    // PV: O^T = mfma32(A = V^T (m = d), B = P), k-steps of 16 keys; V
    // fragments shared across query groups.
#pragma unroll
    for (int db = 0; db < 2; ++db) {
      const int vrow = db * 32 + c;
      const ushort_t* vr = &Vs[cur][vrow * 64];
      bf16x8 vf[4];
#pragma unroll
      for (int s = 0; s < 4; ++s)
        vf[s] = *(const bf16x8*)&vr[(((s << 1) + hh) ^ (vrow & 7)) * 8];
#pragma unroll
      for (int qg = 0; qg < QG; ++qg)
#pragma unroll
        for (int s = 0; s < 4; ++s)
          oacc[qg][db] = mfma32(vf[s], Bf[qg][s], oacc[qg][db]);
    }
  }

  // epilogue: l(query c) = l_acc(h0) + l_acc(h1); O^T reg r of dblk db is
  // d = db*32 + (r&3) + 8*(r>>2) + 4*hh, query = c.
#pragma unroll
  for (int qg = 0; qg < QG; ++qg) {
    float l = l_acc[qg] + __shfl_xor(l_acc[qg], 32);
    float inv = 1.f / l;
    ushort_t* op = O + ((size_t)b * N + q0 + qg * 32 + c) * os + o_ch + h * 64;
#pragma unroll
    for (int db = 0; db < 2; ++db) {
#pragma unroll
      for (int g = 0; g < 4; ++g) {
        uint2 pkv;
        pkv.x = pk_bf16(oacc[qg][db][4 * g + 0] * inv, oacc[qg][db][4 * g + 1] * inv);
        pkv.y = pk_bf16(oacc[qg][db][4 * g + 2] * inv, oacc[qg][db][4 * g + 3] * inv);
        *(uint2*)&op[db * 32 + g * 8 + hh * 4] = pkv;
      }
    }
  }
}

// ---------------------------------------------------------------------------
// V transpose: in [B*N][ld] bf16 (channel ch, head h) -> out [B*H][64][N]
// ---------------------------------------------------------------------------
__global__ __launch_bounds__(256)
void transpose_v(const ushort_t* __restrict__ in, int ld, int ch,
                 ushort_t* __restrict__ out, int N, int H)
{
  __shared__ __align__(16) ushort_t T[64][72];
  const int s0 = blockIdx.x * 64, h = blockIdx.y, b = blockIdx.z;
  const int tid = threadIdx.x;
#pragma unroll
  for (int p = 0; p < 2; ++p) {
    int c = p * 256 + tid;
    int sr = c >> 3, d0 = (c & 7) * 8;
    *(uint4*)&T[sr][d0] =
        *(const uint4*)&in[((size_t)b * N + s0 + sr) * ld + ch + h * 64 + d0];
  }
  __syncthreads();
  const int d = tid >> 2, sp = (tid & 3) * 16;
  union { uint4 v; ushort_t u[8]; } A, B;
#pragma unroll
  for (int j = 0; j < 8; ++j) { A.u[j] = T[sp + j][d]; B.u[j] = T[sp + 8 + j][d]; }
  ushort_t* op = out + ((size_t)(b * H + h) * 64 + d) * N + s0 + sp;
  *(uint4*)&op[0] = A.v;
  *(uint4*)&op[8] = B.v;
}

// ---------------------------------------------------------------------------
// hifi window attention (2x2 windows, 4 heads). qkv rows stride ld; per-token
// layout [3][4 heads][64]. Output stride 512, cols 0..255.
// (q here is NOT pre-scaled by the GEMM; keeps its own 0.125 + __expf.)
// ---------------------------------------------------------------------------
__global__ __launch_bounds__(256)
void hifi_win(const ushort_t* __restrict__ qkv, int ld, ushort_t* __restrict__ out)
{
  const int bg = blockIdx.x;
  const int b = bg >> 8, g = bg & 255;
  const int head = threadIdx.x >> 6, lane = threadIdx.x & 63;
  const int gh = g >> 4, gw = g & 15;

  int n[4];
  float q[4], k[4], v[4];
#pragma unroll
  for (int t = 0; t < 4; ++t) {
    n[t] = (gh * 2 + (t >> 1)) * 32 + gw * 2 + (t & 1);
    size_t base = ((size_t)b * 1024 + n[t]) * ld + head * 64 + lane;
    q[t] = bf2f(qkv[base]);
    k[t] = bf2f(qkv[base + 256]);
    v[t] = bf2f(qkv[base + 512]);
  }
  float sc[4][4];
#pragma unroll
  for (int t = 0; t < 4; ++t)
#pragma unroll
    for (int s = 0; s < 4; ++s) {
      float p = q[t] * k[s];
#pragma unroll
      for (int off = 32; off >= 1; off >>= 1) p += __shfl_xor(p, off);
      sc[t][s] = p * 0.125f;
    }
#pragma unroll
  for (int t = 0; t < 4; ++t) {
    float m = fmaxf(fmaxf(sc[t][0], sc[t][1]), fmaxf(sc[t][2], sc[t][3]));
    float p0 = __expf(sc[t][0] - m), p1 = __expf(sc[t][1] - m);
    float p2 = __expf(sc[t][2] - m), p3 = __expf(sc[t][3] - m);
    float sum = p0 + p1 + p2 + p3;
    float o = (p0 * v[0] + p1 * v[1] + p2 * v[2] + p3 * v[3]) / sum;
    out[((size_t)b * 1024 + n[t]) * 512 + head * 64 + lane] = f2bf(o);
  }
}

// ---------------------------------------------------------------------------
// Merged weight prep: 7 transposes W[K][N] fp32 -> WT[N][K] bf16 in one launch.
// ---------------------------------------------------------------------------
struct WEnt { const float* W; ushort_t* WT; int K; int N; };
struct WArgs { WEnt e[7]; };

__global__ __launch_bounds__(256)
void w_prep(WArgs a)
{
  WEnt w = a.e[blockIdx.z];
  if ((int)blockIdx.x >= (w.K >> 6) || (int)blockIdx.y >= (w.N >> 6)) return;
  __shared__ float T[64][65];
  const int k0 = blockIdx.x * 64, n0 = blockIdx.y * 64;
  const int tid = threadIdx.x;
#pragma unroll
  for (int p = 0; p < 4; ++p) {
    int c = p * 256 + tid;
    int kr = c >> 4, f4 = (c & 15) * 4;
    float4 v = *(const float4*)&w.W[(size_t)(k0 + kr) * w.N + n0 + f4];
    T[f4 + 0][kr] = v.x; T[f4 + 1][kr] = v.y;
    T[f4 + 2][kr] = v.z; T[f4 + 3][kr] = v.w;
  }
  __syncthreads();
  const int nl = tid >> 2, kp = (tid & 3) * 16;
  union { uint4 v; ushort_t u[8]; } A, B;
#pragma unroll
  for (int j = 0; j < 8; ++j) {
    A.u[j] = f2bf(T[nl][kp + j]);
    B.u[j] = f2bf(T[nl][kp + 8 + j]);
  }
  ushort_t* op = w.WT + (size_t)(n0 + nl) * w.K + k0 + kp;
  *(uint4*)&op[0] = A.v;
  *(uint4*)&op[8] = B.v;
}

// xpe = bf16(x + pos_emb), vectorized x4
__global__ void add_pos(const float* __restrict__ x, const float* __restrict__ pos,
                        ushort_t* __restrict__ xpe)
{
  int idx = blockIdx.x * 256 + threadIdx.x;
  int e = idx * 4;
  float4 xv = *(const float4*)&x[e];
  float4 pv = *(const float4*)&pos[e & (512 * 1024 - 1)];
  uint2 pk;
  pk.x = pk_bf16(xv.x + pv.x, xv.y + pv.y);
  pk.y = pk_bf16(xv.z + pv.z, xv.w + pv.w);
  *(uint2*)&xpe[e] = pk;
}

extern "C" void kernel_launch(void* const* d_in, const int* in_sizes, int n_in,
                              void* d_out, int out_size, void* d_ws, size_t ws_size,
                              hipStream_t stream)
{
  const float* x         = (const float*)d_in[0];
  const float* pos       = (const float*)d_in[1];
  const float* l_q_w     = (const float*)d_in[2];
  const float* l_kv_w    = (const float*)d_in[3];
  const float* l_proj_w  = (const float*)d_in[4];
  const float* l_proj_b  = (const float*)d_in[5];
  const float* h_qkv_w   = (const float*)d_in[6];
  const float* h_proj_w  = (const float*)d_in[7];
  const float* h_proj_b  = (const float*)d_in[8];
  const float* in_proj_w = (const float*)d_in[9];
  const float* in_proj_b = (const float*)d_in[10];
  const float* out_proj_w= (const float*)d_in[11];
  const float* out_proj_b= (const float*)d_in[12];
  float* out = (float*)d_out;

  // 0.125 * log2(e): flash_attn uses exp2 directly.
  const float QSCALE = 0.125f * 1.44269504f;

  char* ws = (char*)d_ws;
  ushort_t* xpe = (ushort_t*)(ws);                       // 16 MB @ 0
  ushort_t* y   = (ushort_t*)(ws + (size_t)16777216);    // 16 MB @ 16M
  ushort_t* F   = (ushort_t*)(ws + (size_t)33554432);    // 48 MB @ 32M (fused acts)
  ushort_t* rB  = (ushort_t*)(ws + (size_t)83886080);    // 16 MB @ 80M
  ushort_t* wb  = (ushort_t*)(ws + (size_t)100663296);   // ~4 MB @ 96M (weights)

  // fused BT for the xpe GEMM: rows [0,768)=h_qkv, [768,1024)=l_q, [1024,1536)=l_kv
  ushort_t* F_T      = wb;                        // 1536 x 512
  ushort_t* h_projT  = wb + 786432;               // 256 x 256
  ushort_t* l_projT  = wb + 851968;               // 256 x 256
  ushort_t* in_projT = wb + 917504;               // 1536 x 512
  ushort_t* out_projT= wb + 1703936;              // 512 x 512

  const int M = 16384;
  ushort_t* vT_lo = xpe;   // 8 MB; xpe dead after fused GEMM
  ushort_t* vT_m  = rB;    // 16 MB; rB dead after lproj

  WArgs wa;
  wa.e[0] = {h_qkv_w,   F_T,                 512, 768};
  wa.e[1] = {l_q_w,     F_T + 768 * 512,     512, 256};
  wa.e[2] = {l_kv_w,    F_T + 1024 * 512,    512, 512};
  wa.e[3] = {h_proj_w,  h_projT,             256, 256};
  wa.e[4] = {l_proj_w,  l_projT,             256, 256};
  wa.e[5] = {in_proj_w, in_projT,            512, 1536};
  wa.e[6] = {out_proj_w,out_projT,           512, 512};
  w_prep<<<dim3(8, 24, 7), dim3(256), 0, stream>>>(wa);

  add_pos<<<dim3(8192), dim3(256), 0, stream>>>(x, pos, xpe);

  // 1. fused qkv GEMM: [M,512] x [512,1536] -> F (lofi q cols pre-scaled)
  gemm_bt<<<dim3(M / 128, 12), dim3(256), 0, stream>>>(
      xpe, 512, F_T, nullptr, F, nullptr, 1536, 0, 512, QSCALE, 768, 1024);
  // 2. hifi window attention -> rB cols [0,256)
  hifi_win<<<dim3(4096), dim3(256), 0, stream>>>(F, 1536, rB);
  // 3. transpose lofi V (F cols 1280..1535) -> vT_lo (xpe region, now dead)
  transpose_v<<<dim3(16, 4, 16), dim3(256), 0, stream>>>(
      F, 1536, 1280, vT_lo, 1024, 4);
  // 4. lofi attention (4 heads) -> rB cols [256,512)   (QG=1: 512 blocks)
  flash_attn9<1><<<dim3(8, 4, 16), dim3(256), 0, stream>>>(
      F, 1536, 768, F, 1536, 1024, vT_lo, rB, 512, 256, 1024);
  // 5. hifi proj -> y[:, 0:256)
  gemm_bt<<<dim3(M / 128, 2), dim3(256), 0, stream>>>(
      rB, 512, h_projT, h_proj_b, y, nullptr, 512, 0, 256, 1.0f, 0, 0);
  // 6. lofi proj -> y[:, 256:512)
  gemm_bt<<<dim3(M / 128, 2), dim3(256), 0, stream>>>(
      rB + 256, 512, l_projT, l_proj_b, y, nullptr, 512, 256, 256, 1.0f, 0, 0);
  // 7. mha qkv: [M,512] x [512,1536] -> F (q cols pre-scaled)
  gemm_bt<<<dim3(M / 128, 12), dim3(256), 0, stream>>>(
      y, 512, in_projT, in_proj_b, F, nullptr, 1536, 0, 512, QSCALE, 0, 512);
  // 8. transpose mha V (F cols 1024..1535) -> vT_m (rB dead now)
  transpose_v<<<dim3(16, 8, 16), dim3(256), 0, stream>>>(
      F, 1536, 1024, vT_m, 1024, 8);
  // 9. mha attention (8 heads) -> xpe region [M,512]  (QG=2: 64 q/wave,
  //    512 blocks = 2/CU; two independent chains per wave)
  flash_attn9<2><<<dim3(4, 8, 16), dim3(256), 0, stream>>>(
      F, 1536, 0, F, 1536, 512, vT_m, xpe, 512, 0, 1024);
  // 10. out proj -> d_out fp32
  gemm_bt<<<dim3(M / 128, 4), dim3(256), 0, stream>>>(
      xpe, 512, out_projT, out_proj_b, nullptr, out, 512, 0, 512, 1.0f, 0, 0);
}

// Round 6
// 313.724 us; speedup vs baseline: 1.1844x; 1.0690x over previous
//
#include <hip/hip_runtime.h>

typedef unsigned short ushort_t;
typedef short bf16x8 __attribute__((ext_vector_type(8)));
typedef float f32x4 __attribute__((ext_vector_type(4)));
typedef float f32x16 __attribute__((ext_vector_type(16)));

#define DEV __device__ __forceinline__

// round-half-up bf16 (2 ops)
DEV ushort_t f2bf(float f) {
  return (ushort_t)((__float_as_uint(f) + 0x8000u) >> 16);
}
// pack two floats -> 2 bf16 in one u32 (3 ops: add, add, v_perm_b32)
DEV unsigned pk_bf16(float lo, float hi) {
  unsigned a = __float_as_uint(lo) + 0x8000u;
  unsigned b = __float_as_uint(hi) + 0x8000u;
  return __builtin_amdgcn_perm(b, a, 0x07060302);  // {b.hi16, a.hi16}
}
// single-op packed cvt (RNE): lo16 = bf16(lo), hi16 = bf16(hi).
// Same element order as pk_bf16; <=1 ulp rounding difference.
DEV unsigned cvtpk_bf16(float lo, float hi) {
  unsigned r;
  asm("v_cvt_pk_bf16_f32 %0, %1, %2" : "=v"(r) : "v"(lo), "v"(hi));
  return r;
}
DEV float bf2f(ushort_t h) {
  union { unsigned int u; float f; } v; v.u = ((unsigned int)h) << 16;
  return v.f;
}
DEV f32x4 mfma16(bf16x8 a, bf16x8 b, f32x4 c) {
  return __builtin_amdgcn_mfma_f32_16x16x32_bf16(a, b, c, 0, 0, 0);
}
DEV f32x16 mfma32(bf16x8 a, bf16x8 b, f32x16 c) {
  return __builtin_amdgcn_mfma_f32_32x32x16_bf16(a, b, c, 0, 0, 0);
}
// v_permlane32_swap_b32: swaps the UPPER 32 lanes of the first operand with
// the LOWER 32 lanes of the second (gfx950 semantics, verified R4).
// After pl32swap(a,b):  a = [a_lo | b_lo],  b = [a_hi | b_hi]   ([lo|hi]).
DEV void pl32swap(unsigned &a, unsigned &b) {
  asm("v_permlane32_swap_b32 %0, %1" : "+v"(a), "+v"(b));
}
typedef __attribute__((address_space(3))) void lds_void;
typedef const __attribute__((address_space(1))) void glb_void;
DEV void gl_lds16(const void* g, void* l) {
  __builtin_amdgcn_global_load_lds((glb_void*)g, (lds_void*)l, 16, 0, 0);
}

// ---------------------------------------------------------------------------
// bf16 GEMM: C = A[M,K] * BT[N,K]^T (+bias). 128x128 tile, 4 waves, 4x4 MFMA.
// Columns in [sc_lo, sc_hi) get multiplied by scv after bias (Q pre-scaling).
// R5: T1 XCD-chunked remap, m-major within chunk: the blocks sharing an
// A-row-panel (same m0, all n) land on ONE XCD -> A slice (2 MB) + B panel
// L2-resident per XCD instead of A being re-served ~nbn x from L3.
// (R2 lesson: the 256^2 8-phase template loses here -- occupancy/tail.)
// ---------------------------------------------------------------------------
__global__ __launch_bounds__(256)
void gemm_bt(const ushort_t* __restrict__ A, int lda,
             const ushort_t* __restrict__ BT,
             const float* __restrict__ bias,
             ushort_t* __restrict__ Cb, float* __restrict__ Cf,
             int ldc, int coff, int K, float scv, int sc_lo, int sc_hi)
{
  __shared__ __align__(16) ushort_t As[128 * 32];
  __shared__ __align__(16) ushort_t Bs[128 * 32];
  const int tid  = threadIdx.x;
  const int wave = tid >> 6, lane = tid & 63;
  const int quad = lane >> 4, r16 = lane & 15;
  // T1 remap (nwg % 8 == 0 for all call sites): logical n-fastest.
  const int nwg = gridDim.x * gridDim.y;
  const int lin = blockIdx.x + gridDim.x * blockIdx.y;
  const int logical = (lin & 7) * (nwg >> 3) + (lin >> 3);
  const int nbn = gridDim.y;
  const int mb = logical / nbn, nb = logical - mb * nbn;
  const int m0 = mb * 128, n0 = nb * 128;
  const int wm = (wave >> 1) * 64, wn = (wave & 1) * 64;

  f32x4 acc[4][4];
#pragma unroll
  for (int i = 0; i < 4; ++i)
#pragma unroll
    for (int j = 0; j < 4; ++j) acc[i][j] = (f32x4){0.f, 0.f, 0.f, 0.f};

  for (int kc = 0; kc < K; kc += 32) {
#pragma unroll
    for (int p = 0; p < 4; ++p) {
      int wp = p * 4 + wave;                 // 0..15; 0..7 -> As, 8..15 -> Bs
      int lc = ((wp & 7) << 6) + lane;       // chunk 0..511 within array
      int row = lc >> 2, e8 = (lc & 3) * 8;
      if (wp < 8) gl_lds16(&A[(size_t)(m0 + row) * lda + kc + e8], &As[lc * 8]);
      else        gl_lds16(&BT[(size_t)(n0 + row) * K  + kc + e8], &Bs[lc * 8]);
    }
    __syncthreads();
    bf16x8 af[4], bfr[4];
#pragma unroll
    for (int i = 0; i < 4; ++i) {
      af[i]  = *(const bf16x8*)&As[(wm + i * 16 + r16) * 32 + quad * 8];
      bfr[i] = *(const bf16x8*)&Bs[(wn + i * 16 + r16) * 32 + quad * 8];
    }
#pragma unroll
    for (int mi = 0; mi < 4; ++mi)
#pragma unroll
      for (int ni = 0; ni < 4; ++ni)
        acc[mi][ni] = mfma16(af[mi], bfr[ni], acc[mi][ni]);
    __syncthreads();
  }

  // C/D layout: col = lane&15, row = quad*4 + reg  [m89/m91]
#pragma unroll
  for (int mi = 0; mi < 4; ++mi) {
#pragma unroll
    for (int ni = 0; ni < 4; ++ni) {
      int col = n0 + wn + ni * 16 + r16;
      float bv = bias ? bias[col] : 0.f;
      float s = (col >= sc_lo && col < sc_hi) ? scv : 1.0f;
#pragma unroll
      for (int r = 0; r < 4; ++r) {
        int row = m0 + wm + mi * 16 + quad * 4 + r;
        float v = (acc[mi][ni][r] + bv) * s;
        if (Cf) Cf[(size_t)row * ldc + coff + col] = v;
        else    Cb[(size_t)row * ldc + coff + col] = f2bf(v);
      }
    }
  }
}

// ---------------------------------------------------------------------------
// gemm_proj: steps 5+6 merged into ONE launch (R5). Two 16384x256x256 GEMMs
// (hifi proj / lofi proj) that each filled only 1 block/CU as separate
// 256-block grids; merged grid (128,4) = 512 blocks = 2/CU.
// by (after remap): nidx 0,1 -> hifi (A=rB cols 0.., out cols 0..255);
//                   nidx 2,3 -> lofi (A=rB+256, out cols 256..511).
// K=256, lda=ldc=512, bias indexed by local col (size-256 arrays).
// ---------------------------------------------------------------------------
__global__ __launch_bounds__(256)
void gemm_proj(const ushort_t* __restrict__ rB,
               const ushort_t* __restrict__ hT, const ushort_t* __restrict__ lT,
               const float* __restrict__ hb, const float* __restrict__ lb,
               ushort_t* __restrict__ y)
{
  __shared__ __align__(16) ushort_t As[128 * 32];
  __shared__ __align__(16) ushort_t Bs[128 * 32];
  const int tid  = threadIdx.x;
  const int wave = tid >> 6, lane = tid & 63;
  const int quad = lane >> 4, r16 = lane & 15;
  // T1 remap, n-fastest (nwg = 512)
  const int lin = blockIdx.x + 128 * blockIdx.y;
  const int logical = (lin & 7) * 64 + (lin >> 3);
  const int nidx = logical & 3, m0 = (logical >> 2) * 128;
  const int sel = nidx >> 1, n0 = (nidx & 1) * 128;
  const ushort_t* A  = rB + sel * 256;
  const ushort_t* BT = sel ? lT : hT;
  const float* bias  = sel ? lb : hb;
  const int coff = sel * 256;
  const int wm = (wave >> 1) * 64, wn = (wave & 1) * 64;

  f32x4 acc[4][4];
#pragma unroll
  for (int i = 0; i < 4; ++i)
#pragma unroll
    for (int j = 0; j < 4; ++j) acc[i][j] = (f32x4){0.f, 0.f, 0.f, 0.f};

  for (int kc = 0; kc < 256; kc += 32) {
#pragma unroll
    for (int p = 0; p < 4; ++p) {
      int wp = p * 4 + wave;
      int lc = ((wp & 7) << 6) + lane;
      int row = lc >> 2, e8 = (lc & 3) * 8;
      if (wp < 8) gl_lds16(&A[(size_t)(m0 + row) * 512 + kc + e8], &As[lc * 8]);
      else        gl_lds16(&BT[(size_t)(n0 + row) * 256 + kc + e8], &Bs[lc * 8]);
    }
    __syncthreads();
    bf16x8 af[4], bfr[4];
#pragma unroll
    for (int i = 0; i < 4; ++i) {
      af[i]  = *(const bf16x8*)&As[(wm + i * 16 + r16) * 32 + quad * 8];
      bfr[i] = *(const bf16x8*)&Bs[(wn + i * 16 + r16) * 32 + quad * 8];
    }
#pragma unroll
    for (int mi = 0; mi < 4; ++mi)
#pragma unroll
      for (int ni = 0; ni < 4; ++ni)
        acc[mi][ni] = mfma16(af[mi], bfr[ni], acc[mi][ni]);
    __syncthreads();
  }

#pragma unroll
  for (int mi = 0; mi < 4; ++mi) {
#pragma unroll
    for (int ni = 0; ni < 4; ++ni) {
      int col = n0 + wn + ni * 16 + r16;
      float bv = bias[col];
#pragma unroll
      for (int r = 0; r < 4; ++r) {
        int row = m0 + wm + mi * 16 + quad * 4 + r;
        y[(size_t)row * 512 + coff + col] = f2bf(acc[mi][ni][r] + bv);
      }
    }
  }
}

// ---------------------------------------------------------------------------
// Flash attention v10b: QG independent 32-query groups per wave (templated).
// R5 change: P-pack and epilogue use v_cvt_pk_bf16_f32 (1 op) instead of the
// 3-op round-half-up pk_bf16 -- saves 64 VALU ops/iter/wave at QG=2 (~13% of
// the VALU pipe, which is the busiest at 44%).
// Note: SQ_LDS_BANK_CONFLICT == 16 cyc per gl_lds16 write burst (fixed DMA
// property, measured R1/R4/R5 invariant) -- not a layout issue; ds_reads are
// conflict-free under the 3-bit XOR swizzle.
// 32x32x16 MFMA; S^T = mfma32(K, Q), C-layout col=query=lane&31,
// row=key=(r&3)+8*(r>>2)+4*(lane>>5). P-transform: 16 cvt_pk + 4
// permlane32_swap per group-tile. NO ONLINE MAX (scores pre-scaled by
// 0.125*log2e in the QKV GEMM; exp2 fp32-safe; softmax shift-invariant).
// ---------------------------------------------------------------------------
template<int QG>
__global__ __launch_bounds__(256, 2)
void flash_attn9(const ushort_t* __restrict__ Q, int qs, int q_ch,
                 const ushort_t* __restrict__ Kg, int ks, int k_ch,
                 const ushort_t* __restrict__ vT,
                 ushort_t* __restrict__ O, int os, int o_ch,
                 int N)
{
  // [buf][64 rows][64 bf16] ; K rows = keys (cols d), V rows = d (cols keys)
  __shared__ __align__(16) ushort_t Ks[2][64 * 64];
  __shared__ __align__(16) ushort_t Vs[2][64 * 64];

  const int H = gridDim.y;
  const int tid = threadIdx.x, wave = tid >> 6, lane = tid & 63;
  const int c = lane & 31, hh = lane >> 5;

  // T1: chunked XCD remap (bijective; nwg % 8 == 0).
  const int nwg = gridDim.x * H * gridDim.z;
  const int lin = blockIdx.x + gridDim.x * (blockIdx.y + H * blockIdx.z);
  const int logical = (lin & 7) * (nwg >> 3) + (lin >> 3);
  const int QBS = 8 / QG;                  // q-blocks per (b,h)
  const int qb = logical & (QBS - 1);
  const int t8 = logical / QBS;
  const int b = (H == 8) ? (t8 >> 3) : (t8 >> 2);
  const int h = t8 - b * H;
  const int q0 = qb * (128 * QG) + wave * (32 * QG);

  // Q fragments: B-operand layout B[k=d][n=query]: lane (hh,c) holds
  // query q0+qg*32+c, d = s*16 + hh*8 + j -> qf[qg][s] at byte-col s*16+hh*8.
  bf16x8 qf[QG][4];
#pragma unroll
  for (int qg = 0; qg < QG; ++qg) {
    const ushort_t* qp =
        Q + ((size_t)b * N + q0 + qg * 32 + c) * qs + q_ch + h * 64 + hh * 8;
#pragma unroll
    for (int s = 0; s < 4; ++s) qf[qg][s] = *(const bf16x8*)&qp[s * 16];
  }
  const ushort_t* kbase = Kg + ((size_t)b * N) * ks + k_ch + h * 64;
  const ushort_t* vbase = vT + ((size_t)(b * H + h) * 64) * N;

  f32x16 oacc[QG][2];
#pragma unroll
  for (int qg = 0; qg < QG; ++qg)
#pragma unroll
    for (int i = 0; i < 16; ++i) { oacc[qg][0][i] = 0.f; oacc[qg][1][i] = 0.f; }
  float l_acc[QG];
#pragma unroll
  for (int qg = 0; qg < QG; ++qg) l_acc[qg] = 0.f;

  auto stage = [&](int s0, int buf) {
#pragma unroll
    for (int p = 0; p < 4; ++p) {
      int wp = p * 4 + wave;                 // 0..15: 0..7 -> K, 8..15 -> V
      int lc = ((wp & 7) << 6) + lane;       // chunk 0..511 within tile
      int row = lc >> 3, cc = lc & 7;
      int e8 = ((cc ^ (row & 7)) * 8);       // inverse-swizzled SOURCE chunk
      if (wp < 8) gl_lds16(kbase + (size_t)(s0 + row) * ks + e8, &Ks[buf][lc * 8]);
      else        gl_lds16(vbase + (size_t)row * N + s0 + e8,    &Vs[buf][lc * 8]);
    }
  };

  stage(0, 0);
  const int NT = N >> 6;
  for (int it = 0; it < NT; ++it) {
    const int cur = it & 1;
    __syncthreads();                     // vmcnt(0) drain: tile `it` staged;
                                         // also fences prev-iter LDS readers
    if (it + 1 < NT) stage((it + 1) << 6, cur ^ 1);

    bf16x8 Bf[QG][4];                    // PV B-operand, k-steps of 16 keys
#pragma unroll
    for (int kb = 0; kb < 2; ++kb) {
      // K fragments shared across the QG query groups.
      const int krow = kb * 32 + c;
      const ushort_t* kr = &Ks[cur][krow * 64];
      bf16x8 kf[4];
#pragma unroll
      for (int s = 0; s < 4; ++s)
        kf[s] = *(const bf16x8*)&kr[(((s << 1) + hh) ^ (krow & 7)) * 8];

#pragma unroll
      for (int qg = 0; qg < QG; ++qg) {
        // S^T block: A = K rows (m = key kb*32 + (lane&31)), B = Q[qg].
        f32x16 z;
#pragma unroll
        for (int i = 0; i < 16; ++i) z[i] = 0.f;
#pragma unroll
        for (int s = 0; s < 4; ++s) z = mfma32(kf[s], qf[qg][s], z);
        // exp + pack: reg r <-> key kb*32 + (r&3) + 8*(r>>2) + 4*hh
        float ts = 0.f;
        unsigned W[8];
#pragma unroll
        for (int t = 0; t < 8; ++t) {
          float p0 = __builtin_amdgcn_exp2f(z[2 * t]);
          float p1 = __builtin_amdgcn_exp2f(z[2 * t + 1]);
          ts += p0 + p1;
          W[t] = cvtpk_bf16(p0, p1);
        }
        l_acc[qg] += ts;
        // B[k=hh*8+j][n=c] per k-step, element i = keys {s*16+hh*8+2i, +1}:
        //  u0=[W0_lo|W2_lo] u1=[W1_lo|W3_lo] u2=[W0_hi|W2_hi] u3=[W1_hi|W3_hi]
        // swap(a,b): a=[a_lo|b_lo], b=[a_hi|b_hi] -> swap(W0,W2)=(u0,u2),
        // swap(W1,W3)=(u1,u3); W4..W7 for the second k-step.  [verified R4]
        union U8 { bf16x8 f; unsigned u[4]; } f0, f1;
        unsigned a0 = W[0], b0 = W[2]; pl32swap(a0, b0);
        unsigned a1 = W[1], b1 = W[3]; pl32swap(a1, b1);
        f0.u[0] = a0; f0.u[1] = a1; f0.u[2] = b0; f0.u[3] = b1;
        unsigned a2 = W[4], b2 = W[6]; pl32swap(a2, b2);
        unsigned a3 = W[5], b3 = W[7]; pl32swap(a3, b3);
        f1.u[0] = a2; f1.u[1] = a3; f1.u[2] = b2; f1.u[3] = b3;
        Bf[qg][kb * 2]     = f0.f;
        Bf[qg][kb * 2 + 1] = f1.f;
      }
    }

    // PV: O^T = mfma32(A = V^T (m = d), B = P), k-steps of 16 keys; V
    // fragments shared across query groups.
#pragma unroll
    for (int db = 0; db < 2; ++db) {
      const int vrow = db * 32 + c;
      const ushort_t* vr = &Vs[cur][vrow * 64];
      bf16x8 vf[4];
#pragma unroll
      for (int s = 0; s < 4; ++s)
        vf[s] = *(const bf16x8*)&vr[(((s << 1) + hh) ^ (vrow & 7)) * 8];
#pragma unroll
      for (int qg = 0; qg < QG; ++qg)
#pragma unroll
        for (int s = 0; s < 4; ++s)
          oacc[qg][db] = mfma32(vf[s], Bf[qg][s], oacc[qg][db]);
    }
  }

  // epilogue: l(query c) = l_acc(h0) + l_acc(h1); O^T reg r of dblk db is
  // d = db*32 + (r&3) + 8*(r>>2) + 4*hh, query = c.
#pragma unroll
  for (int qg = 0; qg < QG; ++qg) {
    float l = l_acc[qg] + __shfl_xor(l_acc[qg], 32);
    float inv = 1.f / l;
    ushort_t* op = O + ((size_t)b * N + q0 + qg * 32 + c) * os + o_ch + h * 64;
#pragma unroll
    for (int db = 0; db < 2; ++db) {
#pragma unroll
      for (int g = 0; g < 4; ++g) {
        uint2 pkv;
        pkv.x = cvtpk_bf16(oacc[qg][db][4 * g + 0] * inv, oacc[qg][db][4 * g + 1] * inv);
        pkv.y = cvtpk_bf16(oacc[qg][db][4 * g + 2] * inv, oacc[qg][db][4 * g + 3] * inv);
        *(uint2*)&op[db * 32 + g * 8 + hh * 4] = pkv;
      }
    }
  }
}

// ---------------------------------------------------------------------------
// V transpose: in [B*N][ld] bf16 (channel ch, head h) -> out [B*H][64][N]
// ---------------------------------------------------------------------------
__global__ __launch_bounds__(256)
void transpose_v(const ushort_t* __restrict__ in, int ld, int ch,
                 ushort_t* __restrict__ out, int N, int H)
{
  __shared__ __align__(16) ushort_t T[64][72];
  const int s0 = blockIdx.x * 64, h = blockIdx.y, b = blockIdx.z;
  const int tid = threadIdx.x;
#pragma unroll
  for (int p = 0; p < 2; ++p) {
    int c = p * 256 + tid;
    int sr = c >> 3, d0 = (c & 7) * 8;
    *(uint4*)&T[sr][d0] =
        *(const uint4*)&in[((size_t)b * N + s0 + sr) * ld + ch + h * 64 + d0];
  }
  __syncthreads();
  const int d = tid >> 2, sp = (tid & 3) * 16;
  union { uint4 v; ushort_t u[8]; } A, B;
#pragma unroll
  for (int j = 0; j < 8; ++j) { A.u[j] = T[sp + j][d]; B.u[j] = T[sp + 8 + j][d]; }
  ushort_t* op = out + ((size_t)(b * H + h) * 64 + d) * N + s0 + sp;
  *(uint4*)&op[0] = A.v;
  *(uint4*)&op[8] = B.v;
}

// ---------------------------------------------------------------------------
// hifi window attention (2x2 windows, 4 heads). qkv rows stride ld; per-token
// layout [3][4 heads][64]. Output stride 512, cols 0..255.
// (q here is NOT pre-scaled by the GEMM; keeps its own 0.125 + __expf.)
// ---------------------------------------------------------------------------
__global__ __launch_bounds__(256)
void hifi_win(const ushort_t* __restrict__ qkv, int ld, ushort_t* __restrict__ out)
{
  const int bg = blockIdx.x;
  const int b = bg >> 8, g = bg & 255;
  const int head = threadIdx.x >> 6, lane = threadIdx.x & 63;
  const int gh = g >> 4, gw = g & 15;

  int n[4];
  float q[4], k[4], v[4];
#pragma unroll
  for (int t = 0; t < 4; ++t) {
    n[t] = (gh * 2 + (t >> 1)) * 32 + gw * 2 + (t & 1);
    size_t base = ((size_t)b * 1024 + n[t]) * ld + head * 64 + lane;
    q[t] = bf2f(qkv[base]);
    k[t] = bf2f(qkv[base + 256]);
    v[t] = bf2f(qkv[base + 512]);
  }
  float sc[4][4];
#pragma unroll
  for (int t = 0; t < 4; ++t)
#pragma unroll
    for (int s = 0; s < 4; ++s) {
      float p = q[t] * k[s];
#pragma unroll
      for (int off = 32; off >= 1; off >>= 1) p += __shfl_xor(p, off);
      sc[t][s] = p * 0.125f;
    }
#pragma unroll
  for (int t = 0; t < 4; ++t) {
    float m = fmaxf(fmaxf(sc[t][0], sc[t][1]), fmaxf(sc[t][2], sc[t][3]));
    float p0 = __expf(sc[t][0] - m), p1 = __expf(sc[t][1] - m);
    float p2 = __expf(sc[t][2] - m), p3 = __expf(sc[t][3] - m);
    float sum = p0 + p1 + p2 + p3;
    float o = (p0 * v[0] + p1 * v[1] + p2 * v[2] + p3 * v[3]) / sum;
    out[((size_t)b * 1024 + n[t]) * 512 + head * 64 + lane] = f2bf(o);
  }
}

// ---------------------------------------------------------------------------
// Merged weight prep: 7 transposes W[K][N] fp32 -> WT[N][K] bf16 in one launch.
// ---------------------------------------------------------------------------
struct WEnt { const float* W; ushort_t* WT; int K; int N; };
struct WArgs { WEnt e[7]; };

__global__ __launch_bounds__(256)
void w_prep(WArgs a)
{
  WEnt w = a.e[blockIdx.z];
  if ((int)blockIdx.x >= (w.K >> 6) || (int)blockIdx.y >= (w.N >> 6)) return;
  __shared__ float T[64][65];
  const int k0 = blockIdx.x * 64, n0 = blockIdx.y * 64;
  const int tid = threadIdx.x;
#pragma unroll
  for (int p = 0; p < 4; ++p) {
    int c = p * 256 + tid;
    int kr = c >> 4, f4 = (c & 15) * 4;
    float4 v = *(const float4*)&w.W[(size_t)(k0 + kr) * w.N + n0 + f4];
    T[f4 + 0][kr] = v.x; T[f4 + 1][kr] = v.y;
    T[f4 + 2][kr] = v.z; T[f4 + 3][kr] = v.w;
  }
  __syncthreads();
  const int nl = tid >> 2, kp = (tid & 3) * 16;
  union { uint4 v; ushort_t u[8]; } A, B;
#pragma unroll
  for (int j = 0; j < 8; ++j) {
    A.u[j] = f2bf(T[nl][kp + j]);
    B.u[j] = f2bf(T[nl][kp + 8 + j]);
  }
  ushort_t* op = w.WT + (size_t)(n0 + nl) * w.K + k0 + kp;
  *(uint4*)&op[0] = A.v;
  *(uint4*)&op[8] = B.v;
}

// xpe = bf16(x + pos_emb), vectorized x4
__global__ void add_pos(const float* __restrict__ x, const float* __restrict__ pos,
                        ushort_t* __restrict__ xpe)
{
  int idx = blockIdx.x * 256 + threadIdx.x;
  int e = idx * 4;
  float4 xv = *(const float4*)&x[e];
  float4 pv = *(const float4*)&pos[e & (512 * 1024 - 1)];
  uint2 pk;
  pk.x = pk_bf16(xv.x + pv.x, xv.y + pv.y);
  pk.y = pk_bf16(xv.z + pv.z, xv.w + pv.w);
  *(uint2*)&xpe[e] = pk;
}

extern "C" void kernel_launch(void* const* d_in, const int* in_sizes, int n_in,
                              void* d_out, int out_size, void* d_ws, size_t ws_size,
                              hipStream_t stream)
{
  const float* x         = (const float*)d_in[0];
  const float* pos       = (const float*)d_in[1];
  const float* l_q_w     = (const float*)d_in[2];
  const float* l_kv_w    = (const float*)d_in[3];
  const float* l_proj_w  = (const float*)d_in[4];
  const float* l_proj_b  = (const float*)d_in[5];
  const float* h_qkv_w   = (const float*)d_in[6];
  const float* h_proj_w  = (const float*)d_in[7];
  const float* h_proj_b  = (const float*)d_in[8];
  const float* in_proj_w = (const float*)d_in[9];
  const float* in_proj_b = (const float*)d_in[10];
  const float* out_proj_w= (const float*)d_in[11];
  const float* out_proj_b= (const float*)d_in[12];
  float* out = (float*)d_out;

  // 0.125 * log2(e): flash_attn uses exp2 directly.
  const float QSCALE = 0.125f * 1.44269504f;

  char* ws = (char*)d_ws;
  ushort_t* xpe = (ushort_t*)(ws);                       // 16 MB @ 0
  ushort_t* y   = (ushort_t*)(ws + (size_t)16777216);    // 16 MB @ 16M
  ushort_t* F   = (ushort_t*)(ws + (size_t)33554432);    // 48 MB @ 32M (fused acts)
  ushort_t* rB  = (ushort_t*)(ws + (size_t)83886080);    // 16 MB @ 80M
  ushort_t* wb  = (ushort_t*)(ws + (size_t)100663296);   // ~4 MB @ 96M (weights)

  // fused BT for the xpe GEMM: rows [0,768)=h_qkv, [768,1024)=l_q, [1024,1536)=l_kv
  ushort_t* F_T      = wb;                        // 1536 x 512
  ushort_t* h_projT  = wb + 786432;               // 256 x 256
  ushort_t* l_projT  = wb + 851968;               // 256 x 256
  ushort_t* in_projT = wb + 917504;               // 1536 x 512
  ushort_t* out_projT= wb + 1703936;              // 512 x 512

  const int M = 16384;
  ushort_t* vT_lo = xpe;   // 8 MB; xpe dead after fused GEMM
  ushort_t* vT_m  = rB;    // 16 MB; rB dead after lproj

  WArgs wa;
  wa.e[0] = {h_qkv_w,   F_T,                 512, 768};
  wa.e[1] = {l_q_w,     F_T + 768 * 512,     512, 256};
  wa.e[2] = {l_kv_w,    F_T + 1024 * 512,    512, 512};
  wa.e[3] = {h_proj_w,  h_projT,             256, 256};
  wa.e[4] = {l_proj_w,  l_projT,             256, 256};
  wa.e[5] = {in_proj_w, in_projT,            512, 1536};
  wa.e[6] = {out_proj_w,out_projT,           512, 512};
  w_prep<<<dim3(8, 24, 7), dim3(256), 0, stream>>>(wa);

  add_pos<<<dim3(8192), dim3(256), 0, stream>>>(x, pos, xpe);

  // 1. fused qkv GEMM: [M,512] x [512,1536] -> F (lofi q cols pre-scaled)
  gemm_bt<<<dim3(M / 128, 12), dim3(256), 0, stream>>>(
      xpe, 512, F_T, nullptr, F, nullptr, 1536, 0, 512, QSCALE, 768, 1024);
  // 2. hifi window attention -> rB cols [0,256)
  hifi_win<<<dim3(4096), dim3(256), 0, stream>>>(F, 1536, rB);
  // 3. transpose lofi V (F cols 1280..1535) -> vT_lo (xpe region, now dead)
  transpose_v<<<dim3(16, 4, 16), dim3(256), 0, stream>>>(
      F, 1536, 1280, vT_lo, 1024, 4);
  // 4. lofi attention (4 heads) -> rB cols [256,512)   (QG=1: 512 blocks)
  flash_attn9<1><<<dim3(8, 4, 16), dim3(256), 0, stream>>>(
      F, 1536, 768, F, 1536, 1024, vT_lo, rB, 512, 256, 1024);
  // 5+6. hifi & lofi proj merged -> y  (512 blocks = 2/CU)
  gemm_proj<<<dim3(128, 4), dim3(256), 0, stream>>>(
      rB, h_projT, l_projT, h_proj_b, l_proj_b, y);
  // 7. mha qkv: [M,512] x [512,1536] -> F (q cols pre-scaled)
  gemm_bt<<<dim3(M / 128, 12), dim3(256), 0, stream>>>(
      y, 512, in_projT, in_proj_b, F, nullptr, 1536, 0, 512, QSCALE, 0, 512);
  // 8. transpose mha V (F cols 1024..1535) -> vT_m (rB dead now)
  transpose_v<<<dim3(16, 8, 16), dim3(256), 0, stream>>>(
      F, 1536, 1024, vT_m, 1024, 8);
  // 9. mha attention (8 heads) -> xpe region [M,512]  (QG=2: 64 q/wave,
  //    512 blocks = 2/CU; two independent chains per wave)
  flash_attn9<2><<<dim3(4, 8, 16), dim3(256), 0, stream>>>(
      F, 1536, 0, F, 1536, 512, vT_m, xpe, 512, 0, 1024);
  // 10. out proj -> d_out fp32
  gemm_bt<<<dim3(M / 128, 4), dim3(256), 0, stream>>>(
      xpe, 512, out_projT, out_proj_b, nullptr, out, 512, 0, 512, 1.0f, 0, 0);
}